// Round 5
// baseline (606.269 us; speedup 1.0000x reference)
//
#include <hip/hip_runtime.h>
#include <hip/hip_bf16.h>

#define HH 256
#define SS 128
#define BB 8
#define MM 128
#define DD 256
#define TT 256
#define GG 8    // rows per edge WG
#define NW 8    // waves per WG

// fragment-layout LDS: row stride 33 groups of 16B (odd -> conflict-minimal)
#define ROWG 33
#define FB8 (8 * ROWG * 8)   // ushorts per 8-row phase buffer

typedef float  f32x4  __attribute__((ext_vector_type(4)));
typedef short  bf16x8 __attribute__((ext_vector_type(8)));

__device__ __forceinline__ unsigned short f2bf(float x) {
    unsigned u = __float_as_uint(x);
    return (unsigned short)((u + 0x7fffu + ((u >> 16) & 1u)) >> 16);
}
__device__ __forceinline__ unsigned pk2bf(float a, float b) {
    return (unsigned)f2bf(a) | ((unsigned)f2bf(b) << 16);
}
__device__ __forceinline__ float ftanh(float x) {
    float e = __expf(2.0f * x);
    return 1.0f - 2.0f * __builtin_amdgcn_rcpf(e + 1.0f);
}
__device__ __forceinline__ float fsigm(float x) {
    return __builtin_amdgcn_rcpf(1.0f + __expf(-x));
}

// ---------------- pack 256x256 W (row-major, out x in) into MFMA A-fragments ----------------
__global__ void k_pack(const float* __restrict__ W, unsigned short* __restrict__ pk) {
    int idx = blockIdx.x * 256 + threadIdx.x;   // 8192 = 128 frags * 64 lanes
    int f = idx >> 6, l = idx & 63;
    int ct = f >> 3, kb = f & 7, q = l >> 4, m = l & 15;
    unsigned short out[8];
#pragma unroll
    for (int e = 0; e < 8; e++) {
        int k = kb * 32 + q * 4 + (e & 3) + ((e >> 2) << 4);
        out[e] = f2bf(W[(ct * 16 + m) * HH + k]);
    }
    uint4 v;
    v.x = out[0] | ((unsigned)out[1] << 16);
    v.y = out[2] | ((unsigned)out[3] << 16);
    v.z = out[4] | ((unsigned)out[5] << 16);
    v.w = out[6] | ((unsigned)out[7] << 16);
    *(uint4*)(pk + idx * 8) = v;
}

// ---------------- transpose eW_ih0 (256 x 128) -> (128 x 256) f32 ----------------
__global__ void k_transp(const float* __restrict__ in, float* __restrict__ out) {
    int idx = blockIdx.x * 256 + threadIdx.x;   // 32768
    int j = idx >> 8, c = idx & 255;
    out[idx] = in[c * MM + j];
}

// ---------------- X0T[t][i/4][b][i%4] = input @ gW_ih0^T + gb_ih0 + gb_hh0 ----------------
__global__ void k_x0(const float* __restrict__ x, const float* __restrict__ Wih0,
                     const float* __restrict__ bih0, const float* __restrict__ bhh0,
                     float* __restrict__ X0T) {
    int row = blockIdx.x;           // b*SS + t
    int i = threadIdx.x;
    const float4* xr = (const float4*)(x + row * DD);
    const float4* wr = (const float4*)(Wih0 + i * DD);
    float a0 = 0.f, a1 = 0.f, a2 = 0.f, a3 = 0.f;
#pragma unroll 8
    for (int k = 0; k < DD / 4; k++) {
        float4 xv = xr[k]; float4 wv = wr[k];
        a0 += xv.x * wv.x; a1 += xv.y * wv.y; a2 += xv.z * wv.z; a3 += xv.w * wv.w;
    }
    float val = a0 + a1 + a2 + a3 + bih0[i] + bhh0[i];
    int b = row >> 7, t = row & (SS - 1);
    X0T[t * 2048 + (i >> 2) * 32 + b * 4 + (i & 3)] = val;
}

// ---------------- MFMA fragment loaders ----------------
__device__ __forceinline__ bf16x8 ldA(const unsigned short* __restrict__ pk, int ct, int kb, int lane) {
    return *(const bf16x8*)(pk + (((ct * 8 + kb) * 64 + lane) << 3));
}
// masked B-fragment read: only rows 0-7 are live; lanes rr>=8 deliver zeros
__device__ __forceinline__ bf16x8 ldBm(const unsigned short* base, int rr, int kb, int q) {
    bf16x8 f = {0, 0, 0, 0, 0, 0, 0, 0};
    if (rr < 8) f = *(const bf16x8*)(base + ((rr * ROWG + kb * 4 + q) << 3));
    return f;
}

// ---------------- graph RNN: merged-phase MFMA, weights pinned in VGPR ----------------
// ONE WG, 8 waves, wave wv owns out col-tiles {2wv, 2wv+1}. Phase t (t=0..128):
// computes h0[t] (layer 0) and h1[t-1] (layer 1), sharing the h0[t-1] B-fragments.
__global__ __launch_bounds__(512, 2) void k_graph_mfma(
    const float* __restrict__ X0T, const int* __restrict__ mask,
    const unsigned short* __restrict__ pk0,  // gW_hh0 packed
    const unsigned short* __restrict__ pk1,  // gW_ih1 packed
    const unsigned short* __restrict__ pk2,  // gW_hh1 packed
    const float* __restrict__ bih1, const float* __restrict__ bhh1,
    float* __restrict__ GS) {
    __shared__ alignas(16) unsigned short h0b[2 * FB8];
    __shared__ alignas(16) unsigned short h1b[3 * FB8];
    __shared__ int lenS[8];

    int tid = threadIdx.x;
    int wv = tid >> 6, lane = tid & 63;
    int q = lane >> 4, rr = lane & 15;
    int ct0 = 2 * wv;
    int m0 = 32 * wv + 4 * q;
    int goff = (rr * ROWG + wv * 4 + q) << 3;
    int xoff = (8 * wv + q) * 32 + rr * 4;

    // zero all buffers
    {
        uint4* p0 = (uint4*)h0b;
        for (int idx = tid; idx < 2 * FB8 / 8; idx += 512) p0[idx] = uint4{0, 0, 0, 0};
        uint4* p1 = (uint4*)h1b;
        for (int idx = tid; idx < 3 * FB8 / 8; idx += 512) p1[idx] = uint4{0, 0, 0, 0};
    }
    // lengths: wave wv sums mask row wv
    {
        int s = mask[wv * SS + lane] + mask[wv * SS + 64 + lane];
        for (int off = 32; off; off >>= 1) s += __shfl_xor(s, off);
        if (lane == 0) lenS[wv] = s;
    }
    // weights -> VGPRs (192 regs/lane), pinned via opaque asm
    bf16x8 a0[2][8], a1[2][8], a2[2][8];
#pragma unroll
    for (int kb = 0; kb < 8; kb++) {
        a0[0][kb] = ldA(pk0, ct0, kb, lane); a0[1][kb] = ldA(pk0, ct0 + 1, kb, lane);
        a1[0][kb] = ldA(pk1, ct0, kb, lane); a1[1][kb] = ldA(pk1, ct0 + 1, kb, lane);
        a2[0][kb] = ldA(pk2, ct0, kb, lane); a2[1][kb] = ldA(pk2, ct0 + 1, kb, lane);
    }
#pragma unroll
    for (int kb = 0; kb < 8; kb++) {
        asm volatile("" : "+v"(a0[0][kb]), "+v"(a0[1][kb]),
                          "+v"(a1[0][kb]), "+v"(a1[1][kb]),
                          "+v"(a2[0][kb]), "+v"(a2[1][kb]));
    }
    f32x4 b1A = *(const f32x4*)(bih1 + m0) + *(const f32x4*)(bhh1 + m0);
    f32x4 b1B = *(const f32x4*)(bih1 + m0 + 16) + *(const f32x4*)(bhh1 + m0 + 16);
    __syncthreads();
    int lenr = (rr < 8) ? lenS[rr] : 0;

    // ---- phase 0: h0[0] = masked tanh(X0[0]) (h0[-1]=0 so no MFMA) ----
    {
        bool v0 = 0 < lenr;
        if (rr < 8) {
            const float* xp = X0T + xoff;
            f32x4 xA = *(const f32x4*)xp;
            f32x4 xB = *(const f32x4*)(xp + 128);
            uint4 nv = { pk2bf(ftanh(xA[0]), ftanh(xA[1])), pk2bf(ftanh(xA[2]), ftanh(xA[3])),
                         pk2bf(ftanh(xB[0]), ftanh(xB[1])), pk2bf(ftanh(xB[2]), ftanh(xB[3])) };
            uint4 sv = { v0 ? nv.x : 0u, v0 ? nv.y : 0u, v0 ? nv.z : 0u, v0 ? nv.w : 0u };
            *(uint4*)(h0b + goff) = sv;   // buf 0
        }
        __syncthreads();
    }

    // ---- main phases t=1..127: h0[t] and h1[t-1] ----
    int ir = 2, iw = 0;   // (t-2)%3, (t-1)%3 at t=1
    for (int t = 1; t < SS; t++) {
        const unsigned short* h0r = h0b + ((t - 1) & 1) * FB8;
        const unsigned short* h1r = h1b + ir * FB8;
        f32x4 accA = {0.f, 0.f, 0.f, 0.f}, accB = {0.f, 0.f, 0.f, 0.f};
        if (rr < 8) {
            const float* xp = X0T + t * 2048 + xoff;
            accA = *(const f32x4*)xp;
            accB = *(const f32x4*)(xp + 128);
        }
        f32x4 pA = b1A, pB = b1B;
#pragma unroll
        for (int kb = 0; kb < 8; kb++) {
            bf16x8 h = ldBm(h0r, rr, kb, q);
            bf16x8 g = ldBm(h1r, rr, kb, q);
            accA = __builtin_amdgcn_mfma_f32_16x16x32_bf16(a0[0][kb], h, accA, 0, 0, 0);
            accB = __builtin_amdgcn_mfma_f32_16x16x32_bf16(a0[1][kb], h, accB, 0, 0, 0);
            pA   = __builtin_amdgcn_mfma_f32_16x16x32_bf16(a1[0][kb], h, pA, 0, 0, 0);
            pB   = __builtin_amdgcn_mfma_f32_16x16x32_bf16(a1[1][kb], h, pB, 0, 0, 0);
            pA   = __builtin_amdgcn_mfma_f32_16x16x32_bf16(a2[0][kb], g, pA, 0, 0, 0);
            pB   = __builtin_amdgcn_mfma_f32_16x16x32_bf16(a2[1][kb], g, pB, 0, 0, 0);
        }
        bool v0 = t < lenr;
        bool v1 = (t - 1) < lenr;
        if (rr < 8) {
            // h0[t] write (masked keep from h0[t-1])
            uint4 nv = { pk2bf(ftanh(accA[0]), ftanh(accA[1])), pk2bf(ftanh(accA[2]), ftanh(accA[3])),
                         pk2bf(ftanh(accB[0]), ftanh(accB[1])), pk2bf(ftanh(accB[2]), ftanh(accB[3])) };
            uint4 ov = *(const uint4*)(h0r + goff);
            uint4 sv = { v0 ? nv.x : ov.x, v0 ? nv.y : ov.y, v0 ? nv.z : ov.z, v0 ? nv.w : ov.w };
            *(uint4*)(h0b + (t & 1) * FB8 + goff) = sv;
            // h1[t-1] write (masked keep from h1[t-2]) + GS[t-1]
            float eA[4], eB[4];
#pragma unroll
            for (int r = 0; r < 4; r++) { eA[r] = ftanh(pA[r]); eB[r] = ftanh(pB[r]); }
            uint4 nv1 = { pk2bf(eA[0], eA[1]), pk2bf(eA[2], eA[3]),
                          pk2bf(eB[0], eB[1]), pk2bf(eB[2], eB[3]) };
            uint4 ov1 = *(const uint4*)(h1r + goff);
            uint4 sv1 = { v1 ? nv1.x : ov1.x, v1 ? nv1.y : ov1.y, v1 ? nv1.z : ov1.z, v1 ? nv1.w : ov1.w };
            *(uint4*)(h1b + iw * FB8 + goff) = sv1;
            f32x4 yA, yB;
#pragma unroll
            for (int r = 0; r < 4; r++) { yA[r] = v1 ? eA[r] : 0.f; yB[r] = v1 ? eB[r] : 0.f; }
            float* gp = GS + rr * (SS * HH) + (t - 1) * HH + m0;
            *(f32x4*)gp = yA;
            *(f32x4*)(gp + 16) = yB;
        }
        __syncthreads();
        ir = (ir + 1 == 3) ? 0 : ir + 1;
        iw = (iw + 1 == 3) ? 0 : iw + 1;
    }

    // ---- tail phase t=SS: h1[127] -> GS[127] only ----
    {
        const unsigned short* h0r = h0b + ((SS - 1) & 1) * FB8;
        const unsigned short* h1r = h1b + ir * FB8;
        f32x4 pA = b1A, pB = b1B;
#pragma unroll
        for (int kb = 0; kb < 8; kb++) {
            bf16x8 h = ldBm(h0r, rr, kb, q);
            bf16x8 g = ldBm(h1r, rr, kb, q);
            pA = __builtin_amdgcn_mfma_f32_16x16x32_bf16(a1[0][kb], h, pA, 0, 0, 0);
            pB = __builtin_amdgcn_mfma_f32_16x16x32_bf16(a1[1][kb], h, pB, 0, 0, 0);
            pA = __builtin_amdgcn_mfma_f32_16x16x32_bf16(a2[0][kb], g, pA, 0, 0, 0);
            pB = __builtin_amdgcn_mfma_f32_16x16x32_bf16(a2[1][kb], g, pB, 0, 0, 0);
        }
        bool v1 = (SS - 1) < lenr;
        if (rr < 8) {
            f32x4 yA, yB;
#pragma unroll
            for (int r = 0; r < 4; r++) {
                yA[r] = v1 ? ftanh(pA[r]) : 0.f;
                yB[r] = v1 ? ftanh(pB[r]) : 0.f;
            }
            float* gp = GS + rr * (SS * HH) + (SS - 1) * HH + m0;
            *(f32x4*)gp = yA;
            *(f32x4*)(gp + 16) = yB;
        }
    }
}

// ---------------- edge RNN scan: MFMA, GG=8 rows/WG, weights pinned in VGPR ----------------
__global__ __launch_bounds__(512, 2) void k_edge_mfma(
    const float* __restrict__ GS,
    const unsigned short* __restrict__ pk0,  // eW_hh0 packed
    const unsigned short* __restrict__ pk1,  // eW_ih1 packed
    const unsigned short* __restrict__ pk2,  // eW_hh1 packed
    const float* __restrict__ eWT,           // eW_ih0^T (128 x 256) f32
    const float* __restrict__ bih0, const float* __restrict__ bhh0,
    const float* __restrict__ bih1, const float* __restrict__ bhh1,
    const float* __restrict__ clsW, const float* __restrict__ clsB,
    float* __restrict__ arc) {
    __shared__ alignas(16) unsigned short h0[2 * FB8];
    __shared__ alignas(16) unsigned short h1[2 * FB8];
    __shared__ float red[NW][GG];
    __shared__ float cws[HH];
    __shared__ float b1s[HH];

    int tid = threadIdx.x;
    int wv = tid >> 6, lane = tid & 63;
    int q = lane >> 4, rr = lane & 15;
    int m0 = 32 * wv + 4 * q;
    int goff = (rr * ROWG + wv * 4 + q) << 3;
    int r0 = blockIdx.x * GG;

    // init h0[0] = h1[0] = bf16(GS rows), fragment layout (8 rows x 32 groups)
    if (tid < 256) {
        int r = tid >> 5, g = tid & 31;           // g = kb*4 + qq
        int kb = g >> 2, qq = g & 3;
        int lo = kb * 32 + qq * 4;
        const float* gp = GS + (r0 + r) * HH + lo;
        float4 vlo = *(const float4*)gp;
        float4 vhi = *(const float4*)(gp + 16);
        uint4 pv = { pk2bf(vlo.x, vlo.y), pk2bf(vlo.z, vlo.w),
                     pk2bf(vhi.x, vhi.y), pk2bf(vhi.z, vhi.w) };
        int off = (r * ROWG + g) << 3;
        *(uint4*)(h0 + off) = pv;
        *(uint4*)(h1 + off) = pv;
        cws[tid] = clsW[tid];
        b1s[tid] = bih1[tid] + bhh1[tid];
    }
    // weights -> VGPRs, pinned
    bf16x8 a0[2][8], a1[2][8], a2[2][8];
#pragma unroll
    for (int kb = 0; kb < 8; kb++) {
        a0[0][kb] = ldA(pk0, 2 * wv, kb, lane); a0[1][kb] = ldA(pk0, 2 * wv + 1, kb, lane);
        a1[0][kb] = ldA(pk1, 2 * wv, kb, lane); a1[1][kb] = ldA(pk1, 2 * wv + 1, kb, lane);
        a2[0][kb] = ldA(pk2, 2 * wv, kb, lane); a2[1][kb] = ldA(pk2, 2 * wv + 1, kb, lane);
    }
#pragma unroll
    for (int kb = 0; kb < 8; kb++) {
        asm volatile("" : "+v"(a0[0][kb]), "+v"(a0[1][kb]),
                          "+v"(a1[0][kb]), "+v"(a1[1][kb]),
                          "+v"(a2[0][kb]), "+v"(a2[1][kb]));
    }
    // xw0 in registers (D-layout: lane = (m-slice, row rr); rr>=8 lanes carry garbage, unused)
    f32x4 xw0A = *(const f32x4*)(bih0 + m0) + *(const f32x4*)(bhh0 + m0);
    f32x4 xw0B = *(const f32x4*)(bih0 + m0 + 16) + *(const f32x4*)(bhh0 + m0 + 16);
    float clsb = clsB[0];
    int srow = (r0 + tid) & 127;
    int bidx = (r0 + tid) >> 7;
    __syncthreads();

    for (int j = 0; j < MM; j++) {
        int jr = j & 1, jw = jr ^ 1;
        // prefetch eW_ih0 column j slice (used after B2)
        f32x4 ewA = *(const f32x4*)(eWT + j * HH + m0);
        f32x4 ewB = *(const f32x4*)(eWT + j * HH + m0 + 16);
        // ---- layer 0 ----
        const unsigned short* rb0 = h0 + jr * FB8;
        f32x4 acc0 = xw0A, acc1 = xw0B;
#pragma unroll
        for (int kb = 0; kb < 8; kb++) {
            bf16x8 b = ldBm(rb0, rr, kb, q);
            acc0 = __builtin_amdgcn_mfma_f32_16x16x32_bf16(a0[0][kb], b, acc0, 0, 0, 0);
            acc1 = __builtin_amdgcn_mfma_f32_16x16x32_bf16(a0[1][kb], b, acc1, 0, 0, 0);
        }
        if (rr < 8) {
            uint4 nv = { pk2bf(ftanh(acc0[0]), ftanh(acc0[1])), pk2bf(ftanh(acc0[2]), ftanh(acc0[3])),
                         pk2bf(ftanh(acc1[0]), ftanh(acc1[1])), pk2bf(ftanh(acc1[2]), ftanh(acc1[3])) };
            *(uint4*)(h0 + jw * FB8 + goff) = nv;
        }
        __syncthreads();   // B1: h0[jw] complete
        // ---- layer 1 ----
        const unsigned short* rn = h0 + jw * FB8;
        const unsigned short* r1 = h1 + jr * FB8;
        f32x4 p0 = *(const f32x4*)&b1s[m0];
        f32x4 p1 = *(const f32x4*)&b1s[m0 + 16];
#pragma unroll
        for (int kb = 0; kb < 8; kb++) {
            bf16x8 be = ldBm(rn, rr, kb, q);
            bf16x8 bh = ldBm(r1, rr, kb, q);
            p0 = __builtin_amdgcn_mfma_f32_16x16x32_bf16(a1[0][kb], be, p0, 0, 0, 0);
            p1 = __builtin_amdgcn_mfma_f32_16x16x32_bf16(a1[1][kb], be, p1, 0, 0, 0);
            p0 = __builtin_amdgcn_mfma_f32_16x16x32_bf16(a2[0][kb], bh, p0, 0, 0, 0);
            p1 = __builtin_amdgcn_mfma_f32_16x16x32_bf16(a2[1][kb], bh, p1, 0, 0, 0);
        }
        float e1a[4], e1b[4];
#pragma unroll
        for (int r = 0; r < 4; r++) { e1a[r] = ftanh(p0[r]); e1b[r] = ftanh(p1[r]); }
        if (rr < 8) {
            uint4 nv = { pk2bf(e1a[0], e1a[1]), pk2bf(e1a[2], e1a[3]),
                         pk2bf(e1b[0], e1b[1]), pk2bf(e1b[2], e1b[3]) };
            *(uint4*)(h1 + jw * FB8 + goff) = nv;
        }
        // cls partial over owned 8 cols, reduce over q
        f32x4 cwA = *(const f32x4*)&cws[m0];
        f32x4 cwB = *(const f32x4*)&cws[m0 + 16];
        float part = cwA[0] * e1a[0] + cwA[1] * e1a[1] + cwA[2] * e1a[2] + cwA[3] * e1a[3]
                   + cwB[0] * e1b[0] + cwB[1] * e1b[1] + cwB[2] * e1b[2] + cwB[3] * e1b[3];
        part += __shfl_xor(part, 16);
        part += __shfl_xor(part, 32);
        if (lane < 8) red[wv][lane] = part;
        __syncthreads();   // B2: red + h1[jw] complete
        // ---- all lanes: own-row sigmoid; rank-1 xw0 update in registers ----
        float s = clsb;
#pragma unroll
        for (int w = 0; w < NW; w++) s += red[w][rr & 7];
        float edge = fsigm(s);
        xw0A += edge * ewA;
        xw0B += edge * ewB;
        if (tid < GG) {
            arc[bidx * (MM * SS) + j * SS + srow] = (j < srow) ? edge : 0.f;
        }
        // no barrier: red is re-written only after next B1
    }
}

// ---------------- head/dep tags: elu(GS @ W^T + b) ----------------
__global__ void k_heads(const float* __restrict__ GS,
                        const float* __restrict__ W, const float* __restrict__ bias,
                        float* __restrict__ out) {
    int row = blockIdx.x;
    int i = threadIdx.x;
    const float4* gr = (const float4*)(GS + row * HH);
    const float4* wr = (const float4*)(W + i * HH);
    float a0 = 0.f, a1 = 0.f, a2 = 0.f, a3 = 0.f;
#pragma unroll 8
    for (int k = 0; k < HH / 4; k++) {
        float4 g = gr[k]; float4 w = wr[k];
        a0 += g.x * w.x; a1 += g.y * w.y; a2 += g.z * w.z; a3 += g.w * w.w;
    }
    float v = a0 + a1 + a2 + a3 + bias[i];
    out[row * TT + i] = (v > 0.f) ? v : expm1f(v);
}

extern "C" void kernel_launch(void* const* d_in, const int* in_sizes, int n_in,
                              void* d_out, int out_size, void* d_ws, size_t ws_size,
                              hipStream_t stream) {
    const float* input  = (const float*)d_in[0];
    const int*   mask   = (const int*)d_in[2];
    const float* gW_ih0 = (const float*)d_in[5];
    const float* gW_hh0 = (const float*)d_in[6];
    const float* gb_ih0 = (const float*)d_in[7];
    const float* gb_hh0 = (const float*)d_in[8];
    const float* gW_ih1 = (const float*)d_in[9];
    const float* gW_hh1 = (const float*)d_in[10];
    const float* gb_ih1 = (const float*)d_in[11];
    const float* gb_hh1 = (const float*)d_in[12];
    const float* eW_ih0 = (const float*)d_in[13];
    const float* eW_hh0 = (const float*)d_in[14];
    const float* eb_ih0 = (const float*)d_in[15];
    const float* eb_hh0 = (const float*)d_in[16];
    const float* eW_ih1 = (const float*)d_in[17];
    const float* eW_hh1 = (const float*)d_in[18];
    const float* eb_ih1 = (const float*)d_in[19];
    const float* eb_hh1 = (const float*)d_in[20];
    const float* cls_W  = (const float*)d_in[21];
    const float* cls_b  = (const float*)d_in[22];
    const float* head_W = (const float*)d_in[23];
    const float* head_b = (const float*)d_in[24];
    const float* dep_W  = (const float*)d_in[25];
    const float* dep_b  = (const float*)d_in[26];

    float* out      = (float*)d_out;
    float* head_out = out;                 // 8*128*256
    float* dep_out  = out + 262144;
    float* arc_out  = out + 524288;        // 8*128*128

    char* ws = (char*)d_ws;
    float* X0T = (float*)ws;                                  // 1 MB: [t][i/4][b8][4]
    float* GS  = (float*)(ws + (1 << 20));                    // 1 MB
    unsigned short* pk_g0 = (unsigned short*)(ws + (2 << 20)); // 128 KB each
    unsigned short* pk_g1 = pk_g0 + 65536;
    unsigned short* pk_g2 = pk_g0 + 2 * 65536;
    unsigned short* pk_e0 = pk_g0 + 3 * 65536;
    unsigned short* pk_e1 = pk_g0 + 4 * 65536;
    unsigned short* pk_e2 = pk_g0 + 5 * 65536;
    float* eWT = (float*)(pk_g0 + 6 * 65536);                 // 128 KB

    k_pack<<<32, 256, 0, stream>>>(gW_hh0, pk_g0);
    k_pack<<<32, 256, 0, stream>>>(gW_ih1, pk_g1);
    k_pack<<<32, 256, 0, stream>>>(gW_hh1, pk_g2);
    k_pack<<<32, 256, 0, stream>>>(eW_hh0, pk_e0);
    k_pack<<<32, 256, 0, stream>>>(eW_ih1, pk_e1);
    k_pack<<<32, 256, 0, stream>>>(eW_hh1, pk_e2);
    k_transp<<<128, 256, 0, stream>>>(eW_ih0, eWT);

    k_x0<<<1024, 256, 0, stream>>>(input, gW_ih0, gb_ih0, gb_hh0, X0T);
    k_graph_mfma<<<1, 512, 0, stream>>>(X0T, mask, pk_g0, pk_g1, pk_g2, gb_ih1, gb_hh1, GS);
    k_edge_mfma<<<128, 512, 0, stream>>>(GS, pk_e0, pk_e1, pk_e2, eWT,
                                         eb_ih0, eb_hh0, eb_ih1, eb_hh1, cls_W, cls_b, arc_out);
    k_heads<<<1024, 256, 0, stream>>>(GS, head_W, head_b, head_out);
    k_heads<<<1024, 256, 0, stream>>>(GS, dep_W, dep_b, dep_out);
}

// Round 6
// 557.680 us; speedup vs baseline: 1.0871x; 1.0871x over previous
//
#include <hip/hip_runtime.h>
#include <hip/hip_bf16.h>

#define HH 256
#define SS 128
#define BB 8
#define MM 128
#define DD 256
#define TT 256
#define GG 16   // rows per edge WG
#define NW 8    // waves per WG

// fragment-layout LDS: row stride 33 groups of 16B (odd -> conflict-minimal)
#define ROWG 33
#define FBE (16 * ROWG * 8)  // ushorts per 16-row phase buffer (edge)
#define FB1 (ROWG * 8)       // ushorts per 1-row phase buffer (graph)

typedef float  f32x4  __attribute__((ext_vector_type(4)));
typedef short  bf16x8 __attribute__((ext_vector_type(8)));

__device__ __forceinline__ unsigned short f2bf(float x) {
    unsigned u = __float_as_uint(x);
    return (unsigned short)((u + 0x7fffu + ((u >> 16) & 1u)) >> 16);
}
__device__ __forceinline__ unsigned pk2bf(float a, float b) {
    return (unsigned)f2bf(a) | ((unsigned)f2bf(b) << 16);
}
__device__ __forceinline__ float ftanh(float x) {
    float e = __expf(2.0f * x);
    return 1.0f - 2.0f * __builtin_amdgcn_rcpf(e + 1.0f);
}
__device__ __forceinline__ float fsigm(float x) {
    return __builtin_amdgcn_rcpf(1.0f + __expf(-x));
}

// ---------------- pack 256x256 W (row-major, out x in) into MFMA A-fragments ----------------
__global__ void k_pack(const float* __restrict__ W, unsigned short* __restrict__ pk) {
    int idx = blockIdx.x * 256 + threadIdx.x;   // 8192 = 128 frags * 64 lanes
    int f = idx >> 6, l = idx & 63;
    int ct = f >> 3, kb = f & 7, q = l >> 4, m = l & 15;
    unsigned short out[8];
#pragma unroll
    for (int e = 0; e < 8; e++) {
        int k = kb * 32 + q * 4 + (e & 3) + ((e >> 2) << 4);
        out[e] = f2bf(W[(ct * 16 + m) * HH + k]);
    }
    uint4 v;
    v.x = out[0] | ((unsigned)out[1] << 16);
    v.y = out[2] | ((unsigned)out[3] << 16);
    v.z = out[4] | ((unsigned)out[5] << 16);
    v.w = out[6] | ((unsigned)out[7] << 16);
    *(uint4*)(pk + idx * 8) = v;
}

// ---------------- transpose eW_ih0 (256 x 128) -> (128 x 256) f32 ----------------
__global__ void k_transp(const float* __restrict__ in, float* __restrict__ out) {
    int idx = blockIdx.x * 256 + threadIdx.x;   // 32768
    int j = idx >> 8, c = idx & 255;
    out[idx] = in[c * MM + j];
}

// ---------------- X0T[t][i/4][b][i%4] = input @ gW_ih0^T + gb_ih0 + gb_hh0 ----------------
__global__ void k_x0(const float* __restrict__ x, const float* __restrict__ Wih0,
                     const float* __restrict__ bih0, const float* __restrict__ bhh0,
                     float* __restrict__ X0T) {
    int row = blockIdx.x;           // b*SS + t
    int i = threadIdx.x;
    const float4* xr = (const float4*)(x + row * DD);
    const float4* wr = (const float4*)(Wih0 + i * DD);
    float a0 = 0.f, a1 = 0.f, a2 = 0.f, a3 = 0.f;
#pragma unroll 8
    for (int k = 0; k < DD / 4; k++) {
        float4 xv = xr[k]; float4 wv = wr[k];
        a0 += xv.x * wv.x; a1 += xv.y * wv.y; a2 += xv.z * wv.z; a3 += xv.w * wv.w;
    }
    float val = a0 + a1 + a2 + a3 + bih0[i] + bhh0[i];
    int b = row >> 7, t = row & (SS - 1);
    X0T[t * 2048 + (i >> 2) * 32 + b * 4 + (i & 3)] = val;
}

// ---------------- MFMA fragment loaders ----------------
__device__ __forceinline__ bf16x8 ldA(const unsigned short* __restrict__ pk, int ct, int kb, int lane) {
    return *(const bf16x8*)(pk + (((ct * 8 + kb) * 64 + lane) << 3));
}
__device__ __forceinline__ bf16x8 ldBf(const unsigned short* base, int row, int kb, int q) {
    return *(const bf16x8*)(base + ((row * ROWG + kb * 4 + q) << 3));
}

// ---------------- graph RNN: one WG PER BATCH, weights pinned, B = row-0 broadcast ----------
// 8 WGs x 512 thr. Wave wv owns out col-tiles {2wv,2wv+1}. Phase t computes
// h0[t] and h1[t-1] (merged), 1 barrier/phase. WG-uniform mask => early stop at len.
__global__ __launch_bounds__(512, 2) void k_graph_mfma(
    const float* __restrict__ X0T, const int* __restrict__ mask,
    const unsigned short* __restrict__ pk0,  // gW_hh0 packed
    const unsigned short* __restrict__ pk1,  // gW_ih1 packed
    const unsigned short* __restrict__ pk2,  // gW_hh1 packed
    const float* __restrict__ bih1, const float* __restrict__ bhh1,
    float* __restrict__ GS) {
    __shared__ alignas(16) unsigned short h0b[2 * FB1];
    __shared__ alignas(16) unsigned short h1b[3 * FB1];
    __shared__ int lenS;

    int b = blockIdx.x;
    int tid = threadIdx.x;
    int wv = tid >> 6, lane = tid & 63;
    int q = lane >> 4, rr = lane & 15;
    int ct0 = 2 * wv;
    int m0 = 32 * wv + 4 * q;
    int g16off = (wv * 4 + q) << 3;

    // zero buffers
    {
        unsigned* p0 = (unsigned*)h0b;
        for (int i = tid; i < 2 * FB1 / 2; i += 512) p0[i] = 0;
        unsigned* p1 = (unsigned*)h1b;
        for (int i = tid; i < 3 * FB1 / 2; i += 512) p1[i] = 0;
    }
    if (wv == 0) {
        int s = mask[b * SS + lane] + mask[b * SS + 64 + lane];
        for (int off = 32; off; off >>= 1) s += __shfl_xor(s, off);
        if (lane == 0) lenS = s;
    }
    // weights -> VGPRs (192 regs/lane), pinned
    bf16x8 a0[2][8], a1[2][8], a2[2][8];
#pragma unroll
    for (int kb = 0; kb < 8; kb++) {
        a0[0][kb] = ldA(pk0, ct0, kb, lane); a0[1][kb] = ldA(pk0, ct0 + 1, kb, lane);
        a1[0][kb] = ldA(pk1, ct0, kb, lane); a1[1][kb] = ldA(pk1, ct0 + 1, kb, lane);
        a2[0][kb] = ldA(pk2, ct0, kb, lane); a2[1][kb] = ldA(pk2, ct0 + 1, kb, lane);
    }
#pragma unroll
    for (int kb = 0; kb < 8; kb++) {
        asm volatile("" : "+v"(a0[0][kb]), "+v"(a0[1][kb]),
                          "+v"(a1[0][kb]), "+v"(a1[1][kb]),
                          "+v"(a2[0][kb]), "+v"(a2[1][kb]));
    }
    f32x4 b1A = *(const f32x4*)(bih1 + m0) + *(const f32x4*)(bhh1 + m0);
    f32x4 b1B = *(const f32x4*)(bih1 + m0 + 16) + *(const f32x4*)(bhh1 + m0 + 16);
    __syncthreads();
    int len = lenS;                 // uniform across WG, len >= 64
    bool w0l = (rr == 0);
    const float* xp = X0T + (8 * wv + q) * 32 + b * 4;

    // ---- phase 0: h0[0] = tanh(x0[0]); prefetch x(1) ----
    f32x4 xnA = {0.f,0.f,0.f,0.f}, xnB = {0.f,0.f,0.f,0.f};
    if (w0l) {
        f32x4 xA = *(const f32x4*)xp;
        f32x4 xB = *(const f32x4*)(xp + 128);
        uint4 nv = { pk2bf(ftanh(xA[0]), ftanh(xA[1])), pk2bf(ftanh(xA[2]), ftanh(xA[3])),
                     pk2bf(ftanh(xB[0]), ftanh(xB[1])), pk2bf(ftanh(xB[2]), ftanh(xB[3])) };
        *(uint4*)(h0b + g16off) = nv;
        xnA = *(const f32x4*)(xp + 2048);
        xnB = *(const f32x4*)(xp + 2048 + 128);
    }
    __syncthreads();

    // ---- main phases t=1..len-1: h0[t] and h1[t-1] ----
    int ir = 2, iw = 0;
    for (int t = 1; t < len; t++) {
        const unsigned short* h0r = h0b + ((t - 1) & 1) * FB1;
        const unsigned short* h1r = h1b + ir * FB1;
        f32x4 xcA = xnA, xcB = xnB;
        if (w0l && (t + 1) < SS) {
            xnA = *(const f32x4*)(xp + (t + 1) * 2048);
            xnB = *(const f32x4*)(xp + (t + 1) * 2048 + 128);
        }
        f32x4 accA = {0.f,0.f,0.f,0.f}, accB = {0.f,0.f,0.f,0.f};
        if (w0l) { accA = xcA; accB = xcB; }
        f32x4 pA = b1A, pB = b1B;
#pragma unroll
        for (int kb = 0; kb < 8; kb++) {
            bf16x8 h = ldBf(h0r, 0, kb, q);
            bf16x8 g = ldBf(h1r, 0, kb, q);
            accA = __builtin_amdgcn_mfma_f32_16x16x32_bf16(a0[0][kb], h, accA, 0, 0, 0);
            accB = __builtin_amdgcn_mfma_f32_16x16x32_bf16(a0[1][kb], h, accB, 0, 0, 0);
            pA   = __builtin_amdgcn_mfma_f32_16x16x32_bf16(a1[0][kb], h, pA, 0, 0, 0);
            pB   = __builtin_amdgcn_mfma_f32_16x16x32_bf16(a1[1][kb], h, pB, 0, 0, 0);
            pA   = __builtin_amdgcn_mfma_f32_16x16x32_bf16(a2[0][kb], g, pA, 0, 0, 0);
            pB   = __builtin_amdgcn_mfma_f32_16x16x32_bf16(a2[1][kb], g, pB, 0, 0, 0);
        }
        if (w0l) {
            uint4 nv0 = { pk2bf(ftanh(accA[0]), ftanh(accA[1])), pk2bf(ftanh(accA[2]), ftanh(accA[3])),
                          pk2bf(ftanh(accB[0]), ftanh(accB[1])), pk2bf(ftanh(accB[2]), ftanh(accB[3])) };
            *(uint4*)(h0b + (t & 1) * FB1 + g16off) = nv0;
            float eA[4], eB[4];
#pragma unroll
            for (int r = 0; r < 4; r++) { eA[r] = ftanh(pA[r]); eB[r] = ftanh(pB[r]); }
            uint4 nv1 = { pk2bf(eA[0], eA[1]), pk2bf(eA[2], eA[3]),
                          pk2bf(eB[0], eB[1]), pk2bf(eB[2], eB[3]) };
            *(uint4*)(h1b + iw * FB1 + g16off) = nv1;
            float* gp = GS + b * (SS * HH) + (t - 1) * HH + m0;
            *(f32x4*)gp = f32x4{eA[0], eA[1], eA[2], eA[3]};
            *(f32x4*)(gp + 16) = f32x4{eB[0], eB[1], eB[2], eB[3]};
        }
        __syncthreads();
        ir = (ir + 1 == 3) ? 0 : ir + 1;
        iw = (iw + 1 == 3) ? 0 : iw + 1;
    }

    // ---- tail: h1[len-1] -> GS[len-1] ----
    {
        const unsigned short* h0r = h0b + ((len - 1) & 1) * FB1;
        const unsigned short* h1r = h1b + ir * FB1;
        f32x4 pA = b1A, pB = b1B;
#pragma unroll
        for (int kb = 0; kb < 8; kb++) {
            bf16x8 h = ldBf(h0r, 0, kb, q);
            bf16x8 g = ldBf(h1r, 0, kb, q);
            pA = __builtin_amdgcn_mfma_f32_16x16x32_bf16(a1[0][kb], h, pA, 0, 0, 0);
            pB = __builtin_amdgcn_mfma_f32_16x16x32_bf16(a1[1][kb], h, pB, 0, 0, 0);
            pA = __builtin_amdgcn_mfma_f32_16x16x32_bf16(a2[0][kb], g, pA, 0, 0, 0);
            pB = __builtin_amdgcn_mfma_f32_16x16x32_bf16(a2[1][kb], g, pB, 0, 0, 0);
        }
        if (w0l) {
            float* gp = GS + b * (SS * HH) + (len - 1) * HH + m0;
            *(f32x4*)gp = f32x4{ftanh(pA[0]), ftanh(pA[1]), ftanh(pA[2]), ftanh(pA[3])};
            *(f32x4*)(gp + 16) = f32x4{ftanh(pB[0]), ftanh(pB[1]), ftanh(pB[2]), ftanh(pB[3])};
        }
    }
    // ---- zero GS[len..127] ----
    {
        int total = (SS - len) * HH;
        float* base = GS + b * (SS * HH) + len * HH;
        for (int i = tid; i < total; i += 512) base[i] = 0.f;
    }
}

// ---------------- edge RNN scan: MFMA, GG=16 rows/WG, weights pinned ----------------
__global__ __launch_bounds__(512, 2) void k_edge_mfma(
    const float* __restrict__ GS,
    const unsigned short* __restrict__ pk0,  // eW_hh0 packed
    const unsigned short* __restrict__ pk1,  // eW_ih1 packed
    const unsigned short* __restrict__ pk2,  // eW_hh1 packed
    const float* __restrict__ eWT,           // eW_ih0^T (128 x 256) f32
    const float* __restrict__ bih0, const float* __restrict__ bhh0,
    const float* __restrict__ bih1, const float* __restrict__ bhh1,
    const float* __restrict__ clsW, const float* __restrict__ clsB,
    float* __restrict__ arc) {
    __shared__ alignas(16) unsigned short h0[2 * FBE];
    __shared__ alignas(16) unsigned short h1[2 * FBE];
    __shared__ float red[NW][GG];
    __shared__ float cws[HH];
    __shared__ float b1s[HH];

    int tid = threadIdx.x;
    int wv = tid >> 6, lane = tid & 63;
    int q = lane >> 4, rr = lane & 15;
    int m0 = 32 * wv + 4 * q;
    int goff = (rr * ROWG + wv * 4 + q) << 3;
    int r0 = blockIdx.x * GG;

    // init h0[0] = h1[0] = bf16(GS rows), fragment layout (16 rows x 32 groups = 512 thr)
    {
        int r = tid >> 5, g = tid & 31;           // g = kb*4 + qq
        int kb = g >> 2, qq = g & 3;
        int lo = kb * 32 + qq * 4;
        const float* gp = GS + (r0 + r) * HH + lo;
        float4 vlo = *(const float4*)gp;
        float4 vhi = *(const float4*)(gp + 16);
        uint4 pv = { pk2bf(vlo.x, vlo.y), pk2bf(vlo.z, vlo.w),
                     pk2bf(vhi.x, vhi.y), pk2bf(vhi.z, vhi.w) };
        int off = (r * ROWG + g) << 3;
        *(uint4*)(h0 + off) = pv;
        *(uint4*)(h1 + off) = pv;
    }
    if (tid < HH) {
        cws[tid] = clsW[tid];
        b1s[tid] = bih1[tid] + bhh1[tid];
    }
    // weights -> VGPRs, pinned
    bf16x8 a0[2][8], a1[2][8], a2[2][8];
#pragma unroll
    for (int kb = 0; kb < 8; kb++) {
        a0[0][kb] = ldA(pk0, 2 * wv, kb, lane); a0[1][kb] = ldA(pk0, 2 * wv + 1, kb, lane);
        a1[0][kb] = ldA(pk1, 2 * wv, kb, lane); a1[1][kb] = ldA(pk1, 2 * wv + 1, kb, lane);
        a2[0][kb] = ldA(pk2, 2 * wv, kb, lane); a2[1][kb] = ldA(pk2, 2 * wv + 1, kb, lane);
    }
#pragma unroll
    for (int kb = 0; kb < 8; kb++) {
        asm volatile("" : "+v"(a0[0][kb]), "+v"(a0[1][kb]),
                          "+v"(a1[0][kb]), "+v"(a1[1][kb]),
                          "+v"(a2[0][kb]), "+v"(a2[1][kb]));
    }
    // xw0 in registers (D-layout)
    f32x4 xw0A = *(const f32x4*)(bih0 + m0) + *(const f32x4*)(bhh0 + m0);
    f32x4 xw0B = *(const f32x4*)(bih0 + m0 + 16) + *(const f32x4*)(bhh0 + m0 + 16);
    float clsb = clsB[0];
    int srow = (r0 + tid) & 127;
    int bidx = (r0 + tid) >> 7;
    __syncthreads();

    for (int j = 0; j < MM; j++) {
        int jr = j & 1, jw = jr ^ 1;
        // prefetch eW_ih0 column j slice (used after B2)
        f32x4 ewA = *(const f32x4*)(eWT + j * HH + m0);
        f32x4 ewB = *(const f32x4*)(eWT + j * HH + m0 + 16);
        // ---- layer 0 ----
        const unsigned short* rb0 = h0 + jr * FBE;
        f32x4 acc0 = xw0A, acc1 = xw0B;
#pragma unroll
        for (int kb = 0; kb < 8; kb++) {
            bf16x8 b = ldBf(rb0, rr, kb, q);
            acc0 = __builtin_amdgcn_mfma_f32_16x16x32_bf16(a0[0][kb], b, acc0, 0, 0, 0);
            acc1 = __builtin_amdgcn_mfma_f32_16x16x32_bf16(a0[1][kb], b, acc1, 0, 0, 0);
        }
        {
            uint4 nv = { pk2bf(ftanh(acc0[0]), ftanh(acc0[1])), pk2bf(ftanh(acc0[2]), ftanh(acc0[3])),
                         pk2bf(ftanh(acc1[0]), ftanh(acc1[1])), pk2bf(ftanh(acc1[2]), ftanh(acc1[3])) };
            *(uint4*)(h0 + jw * FBE + goff) = nv;
        }
        __syncthreads();   // B1: h0[jw] complete
        // ---- layer 1 ----
        const unsigned short* rn = h0 + jw * FBE;
        const unsigned short* r1 = h1 + jr * FBE;
        f32x4 p0 = *(const f32x4*)&b1s[m0];
        f32x4 p1 = *(const f32x4*)&b1s[m0 + 16];
#pragma unroll
        for (int kb = 0; kb < 8; kb++) {
            bf16x8 be = ldBf(rn, rr, kb, q);
            bf16x8 bh = ldBf(r1, rr, kb, q);
            p0 = __builtin_amdgcn_mfma_f32_16x16x32_bf16(a1[0][kb], be, p0, 0, 0, 0);
            p1 = __builtin_amdgcn_mfma_f32_16x16x32_bf16(a1[1][kb], be, p1, 0, 0, 0);
            p0 = __builtin_amdgcn_mfma_f32_16x16x32_bf16(a2[0][kb], bh, p0, 0, 0, 0);
            p1 = __builtin_amdgcn_mfma_f32_16x16x32_bf16(a2[1][kb], bh, p1, 0, 0, 0);
        }
        float e1a[4], e1b[4];
#pragma unroll
        for (int r = 0; r < 4; r++) { e1a[r] = ftanh(p0[r]); e1b[r] = ftanh(p1[r]); }
        {
            uint4 nv = { pk2bf(e1a[0], e1a[1]), pk2bf(e1a[2], e1a[3]),
                         pk2bf(e1b[0], e1b[1]), pk2bf(e1b[2], e1b[3]) };
            *(uint4*)(h1 + jw * FBE + goff) = nv;
        }
        // cls partial over owned 8 cols, reduce over q
        f32x4 cwA = *(const f32x4*)&cws[m0];
        f32x4 cwB = *(const f32x4*)&cws[m0 + 16];
        float part = cwA[0] * e1a[0] + cwA[1] * e1a[1] + cwA[2] * e1a[2] + cwA[3] * e1a[3]
                   + cwB[0] * e1b[0] + cwB[1] * e1b[1] + cwB[2] * e1b[2] + cwB[3] * e1b[3];
        part += __shfl_xor(part, 16);
        part += __shfl_xor(part, 32);
        if (lane < 16) red[wv][lane] = part;
        __syncthreads();   // B2: red + h1[jw] complete
        // ---- all lanes: own-row sigmoid; rank-1 xw0 update in registers ----
        float s = clsb;
#pragma unroll
        for (int w = 0; w < NW; w++) s += red[w][rr];
        float edge = fsigm(s);
        xw0A += edge * ewA;
        xw0B += edge * ewB;
        if (tid < GG) {
            arc[bidx * (MM * SS) + j * SS + srow] = (j < srow) ? edge : 0.f;
        }
        // no barrier: red re-written only after next B1; h buffers双-buffered
    }
}

// ---------------- head/dep tags: elu(GS @ W^T + b) ----------------
__global__ void k_heads(const float* __restrict__ GS,
                        const float* __restrict__ W, const float* __restrict__ bias,
                        float* __restrict__ out) {
    int row = blockIdx.x;
    int i = threadIdx.x;
    const float4* gr = (const float4*)(GS + row * HH);
    const float4* wr = (const float4*)(W + i * HH);
    float a0 = 0.f, a1 = 0.f, a2 = 0.f, a3 = 0.f;
#pragma unroll 8
    for (int k = 0; k < HH / 4; k++) {
        float4 g = gr[k]; float4 w = wr[k];
        a0 += g.x * w.x; a1 += g.y * w.y; a2 += g.z * w.z; a3 += g.w * w.w;
    }
    float v = a0 + a1 + a2 + a3 + bias[i];
    out[row * TT + i] = (v > 0.f) ? v : expm1f(v);
}

extern "C" void kernel_launch(void* const* d_in, const int* in_sizes, int n_in,
                              void* d_out, int out_size, void* d_ws, size_t ws_size,
                              hipStream_t stream) {
    const float* input  = (const float*)d_in[0];
    const int*   mask   = (const int*)d_in[2];
    const float* gW_ih0 = (const float*)d_in[5];
    const float* gW_hh0 = (const float*)d_in[6];
    const float* gb_ih0 = (const float*)d_in[7];
    const float* gb_hh0 = (const float*)d_in[8];
    const float* gW_ih1 = (const float*)d_in[9];
    const float* gW_hh1 = (const float*)d_in[10];
    const float* gb_ih1 = (const float*)d_in[11];
    const float* gb_hh1 = (const float*)d_in[12];
    const float* eW_ih0 = (const float*)d_in[13];
    const float* eW_hh0 = (const float*)d_in[14];
    const float* eb_ih0 = (const float*)d_in[15];
    const float* eb_hh0 = (const float*)d_in[16];
    const float* eW_ih1 = (const float*)d_in[17];
    const float* eW_hh1 = (const float*)d_in[18];
    const float* eb_ih1 = (const float*)d_in[19];
    const float* eb_hh1 = (const float*)d_in[20];
    const float* cls_W  = (const float*)d_in[21];
    const float* cls_b  = (const float*)d_in[22];
    const float* head_W = (const float*)d_in[23];
    const float* head_b = (const float*)d_in[24];
    const float* dep_W  = (const float*)d_in[25];
    const float* dep_b  = (const float*)d_in[26];

    float* out      = (float*)d_out;
    float* head_out = out;                 // 8*128*256
    float* dep_out  = out + 262144;
    float* arc_out  = out + 524288;        // 8*128*128

    char* ws = (char*)d_ws;
    float* X0T = (float*)ws;                                  // 1 MB: [t][i/4][b8][4]
    float* GS  = (float*)(ws + (1 << 20));                    // 1 MB
    unsigned short* pk_g0 = (unsigned short*)(ws + (2 << 20)); // 128 KB each
    unsigned short* pk_g1 = pk_g0 + 65536;
    unsigned short* pk_g2 = pk_g0 + 2 * 65536;
    unsigned short* pk_e0 = pk_g0 + 3 * 65536;
    unsigned short* pk_e1 = pk_g0 + 4 * 65536;
    unsigned short* pk_e2 = pk_g0 + 5 * 65536;
    float* eWT = (float*)(pk_g0 + 6 * 65536);                 // 128 KB

    k_pack<<<32, 256, 0, stream>>>(gW_hh0, pk_g0);
    k_pack<<<32, 256, 0, stream>>>(gW_ih1, pk_g1);
    k_pack<<<32, 256, 0, stream>>>(gW_hh1, pk_g2);
    k_pack<<<32, 256, 0, stream>>>(eW_hh0, pk_e0);
    k_pack<<<32, 256, 0, stream>>>(eW_ih1, pk_e1);
    k_pack<<<32, 256, 0, stream>>>(eW_hh1, pk_e2);
    k_transp<<<128, 256, 0, stream>>>(eW_ih0, eWT);

    k_x0<<<1024, 256, 0, stream>>>(input, gW_ih0, gb_ih0, gb_hh0, X0T);
    k_graph_mfma<<<8, 512, 0, stream>>>(X0T, mask, pk_g0, pk_g1, pk_g2, gb_ih1, gb_hh1, GS);
    k_edge_mfma<<<64, 512, 0, stream>>>(GS, pk_e0, pk_e1, pk_e2, eWT,
                                        eb_ih0, eb_hh0, eb_ih1, eb_hh1, cls_W, cls_b, arc_out);
    k_heads<<<1024, 256, 0, stream>>>(GS, head_W, head_b, head_out);
    k_heads<<<1024, 256, 0, stream>>>(GS, dep_W, dep_b, dep_out);
}

// Round 7
// 524.136 us; speedup vs baseline: 1.1567x; 1.0640x over previous
//
#include <hip/hip_runtime.h>
#include <hip/hip_bf16.h>

#define HH 256
#define SS 128
#define BB 8
#define MM 128
#define DD 256
#define TT 256
#define GG 16   // rows per edge WG
#define NW 8    // waves per WG

// fragment-layout LDS: row stride 33 groups of 16B (odd -> conflict-minimal)
#define ROWG 33
#define FBE (16 * ROWG * 8)  // ushorts per 16-row phase buffer (edge)
#define FB1 (ROWG * 8)       // ushorts per 1-row phase buffer (graph)

typedef float  f32x4  __attribute__((ext_vector_type(4)));
typedef short  bf16x8 __attribute__((ext_vector_type(8)));

__device__ __forceinline__ float bflo(unsigned int u) { return __uint_as_float(u << 16); }
__device__ __forceinline__ float bfhi(unsigned int u) { return __uint_as_float(u & 0xffff0000u); }
__device__ __forceinline__ float bfs(unsigned short s) { return __uint_as_float(((unsigned)s) << 16); }
__device__ __forceinline__ unsigned short f2bf(float x) {
    unsigned u = __float_as_uint(x);
    return (unsigned short)((u + 0x7fffu + ((u >> 16) & 1u)) >> 16);
}
__device__ __forceinline__ unsigned pk2bf(float a, float b) {
    return (unsigned)f2bf(a) | ((unsigned)f2bf(b) << 16);
}
__device__ __forceinline__ float ftanh(float x) {
    float e = __expf(2.0f * x);
    return 1.0f - 2.0f * __builtin_amdgcn_rcpf(e + 1.0f);
}
__device__ __forceinline__ float fsigm(float x) {
    return __builtin_amdgcn_rcpf(1.0f + __expf(-x));
}

// ---------------- fused prep: 6 weight packs + eW_ih0 transpose->bf16 ----------------
// grid 224 x 256: blocks [32m..32m+31] pack matrix m (m<6); blocks 192..223 transpose.
__global__ void k_prep(const float* __restrict__ gW_hh0, const float* __restrict__ gW_ih1,
                       const float* __restrict__ gW_hh1, const float* __restrict__ eW_hh0,
                       const float* __restrict__ eW_ih1, const float* __restrict__ eW_hh1,
                       const float* __restrict__ eW_ih0,
                       unsigned short* __restrict__ pk_g0, unsigned short* __restrict__ pk_g1,
                       unsigned short* __restrict__ pk_g2, unsigned short* __restrict__ pk_e0,
                       unsigned short* __restrict__ pk_e1, unsigned short* __restrict__ pk_e2,
                       unsigned short* __restrict__ eWTb) {
    int m = blockIdx.x >> 5;
    int blk = blockIdx.x & 31;
    if (m < 6) {
        const float* W = (m == 0) ? gW_hh0 : (m == 1) ? gW_ih1 : (m == 2) ? gW_hh1
                       : (m == 3) ? eW_hh0 : (m == 4) ? eW_ih1 : eW_hh1;
        unsigned short* pk = (m == 0) ? pk_g0 : (m == 1) ? pk_g1 : (m == 2) ? pk_g2
                           : (m == 3) ? pk_e0 : (m == 4) ? pk_e1 : pk_e2;
        int idx = blk * 256 + threadIdx.x;      // 8192 = 128 frags * 64 lanes
        int f = idx >> 6, l = idx & 63;
        int ct = f >> 3, kb = f & 7, q = l >> 4, mm = l & 15;
        unsigned short out[8];
#pragma unroll
        for (int e = 0; e < 8; e++) {
            int k = kb * 32 + q * 4 + (e & 3) + ((e >> 2) << 4);
            out[e] = f2bf(W[(ct * 16 + mm) * HH + k]);
        }
        uint4 v;
        v.x = out[0] | ((unsigned)out[1] << 16);
        v.y = out[2] | ((unsigned)out[3] << 16);
        v.z = out[4] | ((unsigned)out[5] << 16);
        v.w = out[6] | ((unsigned)out[7] << 16);
        *(uint4*)(pk + idx * 8) = v;
    } else {
        // eWTb[j][c] = bf16(eW_ih0[c][j]); 32768 elems over 32 blocks x 256 thr x 4
        int base = blk * 256 + threadIdx.x;
#pragma unroll
        for (int k = 0; k < 4; k++) {
            int idx = base + k * 8192;
            int j = idx >> 8, c = idx & 255;
            eWTb[idx] = f2bf(eW_ih0[c * MM + j]);
        }
    }
}

// ---------------- X0B[b][t][i] = bf16(input @ gW_ih0^T + gb_ih0 + gb_hh0) ----------------
__global__ void k_x0(const float* __restrict__ x, const float* __restrict__ Wih0,
                     const float* __restrict__ bih0, const float* __restrict__ bhh0,
                     unsigned short* __restrict__ X0B) {
    int row = blockIdx.x;           // b*SS + t
    int i = threadIdx.x;
    const float4* xr = (const float4*)(x + row * DD);
    const float4* wr = (const float4*)(Wih0 + i * DD);
    float a0 = 0.f, a1 = 0.f, a2 = 0.f, a3 = 0.f;
#pragma unroll 8
    for (int k = 0; k < DD / 4; k++) {
        float4 xv = xr[k]; float4 wv = wr[k];
        a0 += xv.x * wv.x; a1 += xv.y * wv.y; a2 += xv.z * wv.z; a3 += xv.w * wv.w;
    }
    X0B[row * HH + i] = f2bf(a0 + a1 + a2 + a3 + bih0[i] + bhh0[i]);
}

// ---------------- MFMA fragment loaders ----------------
__device__ __forceinline__ bf16x8 ldA(const unsigned short* __restrict__ pk, int ct, int kb, int lane) {
    return *(const bf16x8*)(pk + (((ct * 8 + kb) * 64 + lane) << 3));
}
__device__ __forceinline__ bf16x8 ldBf(const unsigned short* base, int row, int kb, int q) {
    return *(const bf16x8*)(base + ((row * ROWG + kb * 4 + q) << 3));
}

// ---------------- graph RNN: one WG per batch; ZERO per-phase global ops ----------------
__global__ __launch_bounds__(512, 2) void k_graph_mfma(
    const unsigned short* __restrict__ X0B, const int* __restrict__ mask,
    const unsigned short* __restrict__ pk0,  // gW_hh0 packed
    const unsigned short* __restrict__ pk1,  // gW_ih1 packed
    const unsigned short* __restrict__ pk2,  // gW_hh1 packed
    const float* __restrict__ bih1, const float* __restrict__ bhh1,
    float* __restrict__ GS) {
    __shared__ alignas(16) unsigned short xs[SS * HH];   // 64 KB: X0 bf16
    __shared__ alignas(16) unsigned short gs[SS * HH];   // 64 KB: GS bf16
    __shared__ alignas(16) unsigned short h0b[2 * FB1];
    __shared__ alignas(16) unsigned short h1b[3 * FB1];
    __shared__ int lenS;

    int b = blockIdx.x;
    int tid = threadIdx.x;
    int wv = tid >> 6, lane = tid & 63;
    int q = lane >> 4, rr = lane & 15;
    int ct0 = 2 * wv;
    int m0 = 32 * wv + 4 * q;
    int g16off = (wv * 4 + q) << 3;

    // zero h buffers
    { unsigned* p = (unsigned*)h0b; for (int i = tid; i < FB1; i += 512) p[i] = 0; }
    { unsigned* p = (unsigned*)h1b; for (int i = tid; i < 3 * FB1 / 2; i += 512) p[i] = 0; }
    // stage X0 slice into LDS (64 KB coalesced)
    {
        const uint4* s = (const uint4*)(X0B + b * SS * HH);
        uint4* d = (uint4*)xs;
        for (int i = tid; i < SS * HH / 8; i += 512) d[i] = s[i];
    }
    if (wv == 0) {
        int s = mask[b * SS + lane] + mask[b * SS + 64 + lane];
        for (int off = 32; off; off >>= 1) s += __shfl_xor(s, off);
        if (lane == 0) lenS = s;
    }
    // weights -> registers (192/lane), pinned
    bf16x8 a0[2][8], a1[2][8], a2[2][8];
#pragma unroll
    for (int kb = 0; kb < 8; kb++) {
        a0[0][kb] = ldA(pk0, ct0, kb, lane); a0[1][kb] = ldA(pk0, ct0 + 1, kb, lane);
        a1[0][kb] = ldA(pk1, ct0, kb, lane); a1[1][kb] = ldA(pk1, ct0 + 1, kb, lane);
        a2[0][kb] = ldA(pk2, ct0, kb, lane); a2[1][kb] = ldA(pk2, ct0 + 1, kb, lane);
    }
#pragma unroll
    for (int kb = 0; kb < 8; kb++) {
        asm volatile("" : "+v"(a0[0][kb]), "+v"(a0[1][kb]),
                          "+v"(a1[0][kb]), "+v"(a1[1][kb]),
                          "+v"(a2[0][kb]), "+v"(a2[1][kb]));
    }
    f32x4 b1A = *(const f32x4*)(bih1 + m0) + *(const f32x4*)(bhh1 + m0);
    f32x4 b1B = *(const f32x4*)(bih1 + m0 + 16) + *(const f32x4*)(bhh1 + m0 + 16);
    __syncthreads();
    int len = lenS;                 // WG-uniform, len >= 64
    bool w0l = (rr == 0);

    // ---- phase 0: h0[0] = tanh(x[0]) ----
    {
        ushort4 xa = *(const ushort4*)(xs + m0);
        ushort4 xb = *(const ushort4*)(xs + m0 + 16);
        if (w0l) {
            uint4 nv = { pk2bf(ftanh(bfs(xa.x)), ftanh(bfs(xa.y))),
                         pk2bf(ftanh(bfs(xa.z)), ftanh(bfs(xa.w))),
                         pk2bf(ftanh(bfs(xb.x)), ftanh(bfs(xb.y))),
                         pk2bf(ftanh(bfs(xb.z)), ftanh(bfs(xb.w))) };
            *(uint4*)(h0b + g16off) = nv;
        }
    }
    __syncthreads();

    // x prefetch for t=1
    ushort4 xcA = *(const ushort4*)(xs + 256 + m0);
    ushort4 xcB = *(const ushort4*)(xs + 256 + m0 + 16);

    // ---- main phases t=1..len-1: h0[t] and h1[t-1], 1 barrier/phase, 0 VMEM ----
    int ir = 2, iw = 0;
    for (int t = 1; t < len; t++) {
        const unsigned short* h0r = h0b + ((t - 1) & 1) * FB1;
        const unsigned short* h1r = h1b + ir * FB1;
        int tn = (t + 1 < SS) ? t + 1 : t;
        ushort4 xnA = *(const ushort4*)(xs + tn * 256 + m0);
        ushort4 xnB = *(const ushort4*)(xs + tn * 256 + m0 + 16);
        f32x4 accA = { bfs(xcA.x), bfs(xcA.y), bfs(xcA.z), bfs(xcA.w) };
        f32x4 accB = { bfs(xcB.x), bfs(xcB.y), bfs(xcB.z), bfs(xcB.w) };
        f32x4 pAe = b1A, pBe = b1B;
        f32x4 pAh = {0.f,0.f,0.f,0.f}, pBh = {0.f,0.f,0.f,0.f};
#pragma unroll
        for (int kb = 0; kb < 8; kb++) {
            bf16x8 h = ldBf(h0r, 0, kb, q);
            bf16x8 g = ldBf(h1r, 0, kb, q);
            accA = __builtin_amdgcn_mfma_f32_16x16x32_bf16(a0[0][kb], h, accA, 0, 0, 0);
            accB = __builtin_amdgcn_mfma_f32_16x16x32_bf16(a0[1][kb], h, accB, 0, 0, 0);
            pAe  = __builtin_amdgcn_mfma_f32_16x16x32_bf16(a1[0][kb], h, pAe, 0, 0, 0);
            pBe  = __builtin_amdgcn_mfma_f32_16x16x32_bf16(a1[1][kb], h, pBe, 0, 0, 0);
            pAh  = __builtin_amdgcn_mfma_f32_16x16x32_bf16(a2[0][kb], g, pAh, 0, 0, 0);
            pBh  = __builtin_amdgcn_mfma_f32_16x16x32_bf16(a2[1][kb], g, pBh, 0, 0, 0);
        }
        if (w0l) {
            uint4 nv0 = { pk2bf(ftanh(accA[0]), ftanh(accA[1])), pk2bf(ftanh(accA[2]), ftanh(accA[3])),
                          pk2bf(ftanh(accB[0]), ftanh(accB[1])), pk2bf(ftanh(accB[2]), ftanh(accB[3])) };
            *(uint4*)(h0b + (t & 1) * FB1 + g16off) = nv0;
            f32x4 pA = pAe + pAh, pB = pBe + pBh;
            float eA[4], eB[4];
#pragma unroll
            for (int r = 0; r < 4; r++) { eA[r] = ftanh(pA[r]); eB[r] = ftanh(pB[r]); }
            uint4 nv1 = { pk2bf(eA[0], eA[1]), pk2bf(eA[2], eA[3]),
                          pk2bf(eB[0], eB[1]), pk2bf(eB[2], eB[3]) };
            *(uint4*)(h1b + iw * FB1 + g16off) = nv1;
            ushort4 ga = { f2bf(eA[0]), f2bf(eA[1]), f2bf(eA[2]), f2bf(eA[3]) };
            ushort4 gb = { f2bf(eB[0]), f2bf(eB[1]), f2bf(eB[2]), f2bf(eB[3]) };
            *(ushort4*)(gs + (t - 1) * 256 + m0) = ga;
            *(ushort4*)(gs + (t - 1) * 256 + m0 + 16) = gb;
        }
        __syncthreads();
        xcA = xnA; xcB = xnB;
        ir = (ir + 1 == 3) ? 0 : ir + 1;
        iw = (iw + 1 == 3) ? 0 : iw + 1;
    }

    // ---- tail: h1[len-1] -> gs[len-1] ----
    {
        const unsigned short* h0r = h0b + ((len - 1) & 1) * FB1;
        const unsigned short* h1r = h1b + ir * FB1;
        f32x4 pAe = b1A, pBe = b1B;
        f32x4 pAh = {0.f,0.f,0.f,0.f}, pBh = {0.f,0.f,0.f,0.f};
#pragma unroll
        for (int kb = 0; kb < 8; kb++) {
            bf16x8 h = ldBf(h0r, 0, kb, q);
            bf16x8 g = ldBf(h1r, 0, kb, q);
            pAe = __builtin_amdgcn_mfma_f32_16x16x32_bf16(a1[0][kb], h, pAe, 0, 0, 0);
            pBe = __builtin_amdgcn_mfma_f32_16x16x32_bf16(a1[1][kb], h, pBe, 0, 0, 0);
            pAh = __builtin_amdgcn_mfma_f32_16x16x32_bf16(a2[0][kb], g, pAh, 0, 0, 0);
            pBh = __builtin_amdgcn_mfma_f32_16x16x32_bf16(a2[1][kb], g, pBh, 0, 0, 0);
        }
        if (w0l) {
            f32x4 pA = pAe + pAh, pB = pBe + pBh;
            ushort4 ga = { f2bf(ftanh(pA[0])), f2bf(ftanh(pA[1])), f2bf(ftanh(pA[2])), f2bf(ftanh(pA[3])) };
            ushort4 gb = { f2bf(ftanh(pB[0])), f2bf(ftanh(pB[1])), f2bf(ftanh(pB[2])), f2bf(ftanh(pB[3])) };
            *(ushort4*)(gs + (len - 1) * 256 + m0) = ga;
            *(ushort4*)(gs + (len - 1) * 256 + m0 + 16) = gb;
        }
    }
    __syncthreads();
    // ---- flush gs -> GS (f32), zeros for t >= len ----
    {
        float* dst = GS + b * (SS * HH);
        const uint4* src = (const uint4*)gs;
        for (int i = tid; i < SS * HH / 8; i += 512) {
            int t = i >> 5;
            float4 f0 = {0.f,0.f,0.f,0.f}, f1 = {0.f,0.f,0.f,0.f};
            if (t < len) {
                uint4 v = src[i];
                f0 = float4{ bflo(v.x), bfhi(v.x), bflo(v.y), bfhi(v.y) };
                f1 = float4{ bflo(v.z), bfhi(v.z), bflo(v.w), bfhi(v.w) };
            }
            *(float4*)(dst + i * 8) = f0;
            *(float4*)(dst + i * 8 + 4) = f1;
        }
    }
}

// ---------------- edge RNN scan: MFMA, GG=16, LDS-resident eW column, LDS arc ----------------
__global__ __launch_bounds__(512, 2) void k_edge_mfma(
    const float* __restrict__ GS,
    const unsigned short* __restrict__ pk0,  // eW_hh0 packed
    const unsigned short* __restrict__ pk1,  // eW_ih1 packed
    const unsigned short* __restrict__ pk2,  // eW_hh1 packed
    const unsigned short* __restrict__ eWTb, // eW_ih0^T bf16 (128 x 256)
    const float* __restrict__ bih0, const float* __restrict__ bhh0,
    const float* __restrict__ bih1, const float* __restrict__ bhh1,
    const float* __restrict__ clsW, const float* __restrict__ clsB,
    float* __restrict__ arc) {
    __shared__ alignas(16) unsigned short h0[2 * FBE];
    __shared__ alignas(16) unsigned short h1[2 * FBE];
    __shared__ alignas(16) unsigned short ews[MM * HH];  // 64 KB
    __shared__ float red[NW][GG];
    __shared__ float cws[HH];
    __shared__ float b1s[HH];
    __shared__ float arcb[GG][MM + 1];

    int tid = threadIdx.x;
    int wv = tid >> 6, lane = tid & 63;
    int q = lane >> 4, rr = lane & 15;
    int m0 = 32 * wv + 4 * q;
    int goff = (rr * ROWG + wv * 4 + q) << 3;
    int r0 = blockIdx.x * GG;

    // stage eWTb into LDS (64 KB coalesced)
    {
        const uint4* s = (const uint4*)eWTb;
        uint4* d = (uint4*)ews;
        for (int i = tid; i < MM * HH / 8; i += 512) d[i] = s[i];
    }
    // init h0[0] = h1[0] = bf16(GS rows), fragment layout (16 rows x 32 groups)
    {
        int r = tid >> 5, g = tid & 31;           // g = kb*4 + qq
        int kb = g >> 2, qq = g & 3;
        int lo = kb * 32 + qq * 4;
        const float* gp = GS + (r0 + r) * HH + lo;
        float4 vlo = *(const float4*)gp;
        float4 vhi = *(const float4*)(gp + 16);
        uint4 pv = { pk2bf(vlo.x, vlo.y), pk2bf(vlo.z, vlo.w),
                     pk2bf(vhi.x, vhi.y), pk2bf(vhi.z, vhi.w) };
        int off = (r * ROWG + g) << 3;
        *(uint4*)(h0 + off) = pv;
        *(uint4*)(h1 + off) = pv;
    }
    if (tid < HH) {
        cws[tid] = clsW[tid];
        b1s[tid] = bih1[tid] + bhh1[tid];
    }
    // weights -> registers, pinned
    bf16x8 a0[2][8], a1[2][8], a2[2][8];
#pragma unroll
    for (int kb = 0; kb < 8; kb++) {
        a0[0][kb] = ldA(pk0, 2 * wv, kb, lane); a0[1][kb] = ldA(pk0, 2 * wv + 1, kb, lane);
        a1[0][kb] = ldA(pk1, 2 * wv, kb, lane); a1[1][kb] = ldA(pk1, 2 * wv + 1, kb, lane);
        a2[0][kb] = ldA(pk2, 2 * wv, kb, lane); a2[1][kb] = ldA(pk2, 2 * wv + 1, kb, lane);
    }
#pragma unroll
    for (int kb = 0; kb < 8; kb++) {
        asm volatile("" : "+v"(a0[0][kb]), "+v"(a0[1][kb]),
                          "+v"(a1[0][kb]), "+v"(a1[1][kb]),
                          "+v"(a2[0][kb]), "+v"(a2[1][kb]));
    }
    // xw0 in registers (D-layout)
    f32x4 xw0A = *(const f32x4*)(bih0 + m0) + *(const f32x4*)(bhh0 + m0);
    f32x4 xw0B = *(const f32x4*)(bih0 + m0 + 16) + *(const f32x4*)(bhh0 + m0 + 16);
    float clsb = clsB[0];
    int srow = (r0 + tid) & 127;
    __syncthreads();

    // ews prefetch for j=0
    ushort4 ewcA = *(const ushort4*)(ews + m0);
    ushort4 ewcB = *(const ushort4*)(ews + m0 + 16);

    for (int j = 0; j < MM; j++) {
        int jr = j & 1, jw = jr ^ 1;
        // ---- layer 0 ----
        const unsigned short* rb0 = h0 + jr * FBE;
        f32x4 acc0 = xw0A, acc1 = xw0B;
#pragma unroll
        for (int kb = 0; kb < 8; kb++) {
            bf16x8 b = ldBf(rb0, rr, kb, q);
            acc0 = __builtin_amdgcn_mfma_f32_16x16x32_bf16(a0[0][kb], b, acc0, 0, 0, 0);
            acc1 = __builtin_amdgcn_mfma_f32_16x16x32_bf16(a0[1][kb], b, acc1, 0, 0, 0);
        }
        {
            uint4 nv = { pk2bf(ftanh(acc0[0]), ftanh(acc0[1])), pk2bf(ftanh(acc0[2]), ftanh(acc0[3])),
                         pk2bf(ftanh(acc1[0]), ftanh(acc1[1])), pk2bf(ftanh(acc1[2]), ftanh(acc1[3])) };
            *(uint4*)(h0 + jw * FBE + goff) = nv;
        }
        __syncthreads();   // B1: h0[jw] complete (LDS-only drain)
        // prefetch ews column j+1 (ews is read-only -> no hazard)
        int jn = (j + 1 < MM) ? j + 1 : j;
        ushort4 ewnA = *(const ushort4*)(ews + jn * HH + m0);
        ushort4 ewnB = *(const ushort4*)(ews + jn * HH + m0 + 16);
        // ---- layer 1 (split 8-dep chains) ----
        const unsigned short* rn = h0 + jw * FBE;
        const unsigned short* r1 = h1 + jr * FBE;
        f32x4 p0e = *(const f32x4*)&b1s[m0];
        f32x4 p1e = *(const f32x4*)&b1s[m0 + 16];
        f32x4 p0h = {0.f,0.f,0.f,0.f}, p1h = {0.f,0.f,0.f,0.f};
#pragma unroll
        for (int kb = 0; kb < 8; kb++) {
            bf16x8 be = ldBf(rn, rr, kb, q);
            bf16x8 bh = ldBf(r1, rr, kb, q);
            p0e = __builtin_amdgcn_mfma_f32_16x16x32_bf16(a1[0][kb], be, p0e, 0, 0, 0);
            p1e = __builtin_amdgcn_mfma_f32_16x16x32_bf16(a1[1][kb], be, p1e, 0, 0, 0);
            p0h = __builtin_amdgcn_mfma_f32_16x16x32_bf16(a2[0][kb], bh, p0h, 0, 0, 0);
            p1h = __builtin_amdgcn_mfma_f32_16x16x32_bf16(a2[1][kb], bh, p1h, 0, 0, 0);
        }
        float e1a[4], e1b[4];
#pragma unroll
        for (int r = 0; r < 4; r++) { e1a[r] = ftanh(p0e[r] + p0h[r]); e1b[r] = ftanh(p1e[r] + p1h[r]); }
        {
            uint4 nv = { pk2bf(e1a[0], e1a[1]), pk2bf(e1a[2], e1a[3]),
                         pk2bf(e1b[0], e1b[1]), pk2bf(e1b[2], e1b[3]) };
            *(uint4*)(h1 + jw * FBE + goff) = nv;
        }
        // cls partial over owned 8 cols, reduce over q-lanes
        f32x4 cwA = *(const f32x4*)&cws[m0];
        f32x4 cwB = *(const f32x4*)&cws[m0 + 16];
        float part = cwA[0] * e1a[0] + cwA[1] * e1a[1] + cwA[2] * e1a[2] + cwA[3] * e1a[3]
                   + cwB[0] * e1b[0] + cwB[1] * e1b[1] + cwB[2] * e1b[2] + cwB[3] * e1b[3];
        part += __shfl_xor(part, 16);
        part += __shfl_xor(part, 32);
        if (lane < 16) red[wv][lane] = part;
        __syncthreads();   // B2: red + h1[jw] complete
        // ---- all lanes: own-row sigmoid; rank-1 xw0 update; arc -> LDS ----
        float s = clsb;
#pragma unroll
        for (int w = 0; w < NW; w++) s += red[w][rr];
        float edge = fsigm(s);
        f32x4 ewA = { bfs(ewcA.x), bfs(ewcA.y), bfs(ewcA.z), bfs(ewcA.w) };
        f32x4 ewB = { bfs(ewcB.x), bfs(ewcB.y), bfs(ewcB.z), bfs(ewcB.w) };
        xw0A += edge * ewA;
        xw0B += edge * ewB;
        if (tid < GG) arcb[tid][j] = (j < srow) ? edge : 0.f;
        ewcA = ewnA; ewcB = ewnB;
        // no barrier: red/arcb re-written only after next B1
    }
    __syncthreads();
    // ---- flush arc buffer ----
    for (int i = tid; i < GG * MM; i += 512) {
        int row = i & 15, j = i >> 4;
        int sr = (r0 + row) & 127, bi = (r0 + row) >> 7;
        arc[bi * (MM * SS) + j * SS + sr] = arcb[row][j];
    }
}

// ---------------- head/dep tags: elu(GS @ W^T + b) ----------------
__global__ void k_heads(const float* __restrict__ GS,
                        const float* __restrict__ W, const float* __restrict__ bias,
                        float* __restrict__ out) {
    int row = blockIdx.x;
    int i = threadIdx.x;
    const float4* gr = (const float4*)(GS + row * HH);
    const float4* wr = (const float4*)(W + i * HH);
    float a0 = 0.f, a1 = 0.f, a2 = 0.f, a3 = 0.f;
#pragma unroll 8
    for (int k = 0; k < HH / 4; k++) {
        float4 g = gr[k]; float4 w = wr[k];
        a0 += g.x * w.x; a1 += g.y * w.y; a2 += g.z * w.z; a3 += g.w * w.w;
    }
    float v = a0 + a1 + a2 + a3 + bias[i];
    out[row * TT + i] = (v > 0.f) ? v : expm1f(v);
}

extern "C" void kernel_launch(void* const* d_in, const int* in_sizes, int n_in,
                              void* d_out, int out_size, void* d_ws, size_t ws_size,
                              hipStream_t stream) {
    const float* input  = (const float*)d_in[0];
    const int*   mask   = (const int*)d_in[2];
    const float* gW_ih0 = (const float*)d_in[5];
    const float* gW_hh0 = (const float*)d_in[6];
    const float* gb_ih0 = (const float*)d_in[7];
    const float* gb_hh0 = (const float*)d_in[8];
    const float* gW_ih1 = (const float*)d_in[9];
    const float* gW_hh1 = (const float*)d_in[10];
    const float* gb_ih1 = (const float*)d_in[11];
    const float* gb_hh1 = (const float*)d_in[12];
    const float* eW_ih0 = (const float*)d_in[13];
    const float* eW_hh0 = (const float*)d_in[14];
    const float* eb_ih0 = (const float*)d_in[15];
    const float* eb_hh0 = (const float*)d_in[16];
    const float* eW_ih1 = (const float*)d_in[17];
    const float* eW_hh1 = (const float*)d_in[18];
    const float* eb_ih1 = (const float*)d_in[19];
    const float* eb_hh1 = (const float*)d_in[20];
    const float* cls_W  = (const float*)d_in[21];
    const float* cls_b  = (const float*)d_in[22];
    const float* head_W = (const float*)d_in[23];
    const float* head_b = (const float*)d_in[24];
    const float* dep_W  = (const float*)d_in[25];
    const float* dep_b  = (const float*)d_in[26];

    float* out      = (float*)d_out;
    float* head_out = out;                 // 8*128*256
    float* dep_out  = out + 262144;
    float* arc_out  = out + 524288;        // 8*128*128

    char* ws = (char*)d_ws;
    unsigned short* X0B = (unsigned short*)ws;                 // 512 KB bf16 [b][t][i]
    float* GS  = (float*)(ws + (1 << 20));                     // 1 MB
    unsigned short* pk_g0 = (unsigned short*)(ws + (2 << 20)); // 128 KB each
    unsigned short* pk_g1 = pk_g0 + 65536;
    unsigned short* pk_g2 = pk_g0 + 2 * 65536;
    unsigned short* pk_e0 = pk_g0 + 3 * 65536;
    unsigned short* pk_e1 = pk_g0 + 4 * 65536;
    unsigned short* pk_e2 = pk_g0 + 5 * 65536;
    unsigned short* eWTb  = pk_g0 + 6 * 65536;                 // 64 KB bf16

    k_prep<<<224, 256, 0, stream>>>(gW_hh0, gW_ih1, gW_hh1, eW_hh0, eW_ih1, eW_hh1, eW_ih0,
                                    pk_g0, pk_g1, pk_g2, pk_e0, pk_e1, pk_e2, eWTb);
    k_x0<<<1024, 256, 0, stream>>>(input, gW_ih0, gb_ih0, gb_hh0, X0B);
    k_graph_mfma<<<8, 512, 0, stream>>>(X0B, mask, pk_g0, pk_g1, pk_g2, gb_ih1, gb_hh1, GS);
    k_edge_mfma<<<64, 512, 0, stream>>>(GS, pk_e0, pk_e1, pk_e2, eWTb,
                                        eb_ih0, eb_hh0, eb_ih1, eb_hh1, cls_W, cls_b, arc_out);
    k_heads<<<1024, 256, 0, stream>>>(GS, head_W, head_b, head_out);
    k_heads<<<1024, 256, 0, stream>>>(GS, dep_W, dep_b, dep_out);
}

// Round 8
// 480.479 us; speedup vs baseline: 1.2618x; 1.0909x over previous
//
#include <hip/hip_runtime.h>
#include <hip/hip_bf16.h>

#define HH 256
#define SS 128
#define BB 8
#define MM 128
#define DD 256
#define TT 256
#define GG 16   // rows per edge WG
#define NW 8    // waves per WG

// fragment-layout LDS: row stride 33 groups of 16B (odd -> conflict-minimal)
#define ROWG 33
#define FBE (16 * ROWG * 8)  // ushorts per 16-row phase buffer (edge)
#define FB1 (ROWG * 8)       // ushorts per 1-row phase buffer (graph)

typedef float  f32x4  __attribute__((ext_vector_type(4)));
typedef short  bf16x8 __attribute__((ext_vector_type(8)));

__device__ __forceinline__ float bflo(unsigned int u) { return __uint_as_float(u << 16); }
__device__ __forceinline__ float bfhi(unsigned int u) { return __uint_as_float(u & 0xffff0000u); }
__device__ __forceinline__ float bfs(unsigned short s) { return __uint_as_float(((unsigned)s) << 16); }
__device__ __forceinline__ unsigned short f2bf(float x) {
    unsigned u = __float_as_uint(x);
    return (unsigned short)((u + 0x7fffu + ((u >> 16) & 1u)) >> 16);
}
__device__ __forceinline__ unsigned pk2bf(float a, float b) {
    return (unsigned)f2bf(a) | ((unsigned)f2bf(b) << 16);
}
__device__ __forceinline__ float ftanh(float x) {
    float e = __expf(2.0f * x);
    return 1.0f - 2.0f * __builtin_amdgcn_rcpf(e + 1.0f);
}
__device__ __forceinline__ float fsigm(float x) {
    return __builtin_amdgcn_rcpf(1.0f + __expf(-x));
}

// ---------------- fused prep: 8 weight packs + eW_ih0 transpose->bf16 ----------------
// grid 288 x 256: blocks [32m..32m+31] pack matrix m (m<8); blocks 256..287 transpose.
__global__ void k_prep(const float* __restrict__ gW_hh0, const float* __restrict__ gW_ih1,
                       const float* __restrict__ gW_hh1, const float* __restrict__ eW_hh0,
                       const float* __restrict__ eW_ih1, const float* __restrict__ eW_hh1,
                       const float* __restrict__ head_W, const float* __restrict__ dep_W,
                       const float* __restrict__ eW_ih0,
                       unsigned short* __restrict__ pk_g0, unsigned short* __restrict__ pk_g1,
                       unsigned short* __restrict__ pk_g2, unsigned short* __restrict__ pk_e0,
                       unsigned short* __restrict__ pk_e1, unsigned short* __restrict__ pk_e2,
                       unsigned short* __restrict__ pk_h0, unsigned short* __restrict__ pk_h1,
                       unsigned short* __restrict__ eWTb) {
    int m = blockIdx.x >> 5;
    int blk = blockIdx.x & 31;
    if (m < 8) {
        const float* W = (m == 0) ? gW_hh0 : (m == 1) ? gW_ih1 : (m == 2) ? gW_hh1
                       : (m == 3) ? eW_hh0 : (m == 4) ? eW_ih1 : (m == 5) ? eW_hh1
                       : (m == 6) ? head_W : dep_W;
        unsigned short* pk = (m == 0) ? pk_g0 : (m == 1) ? pk_g1 : (m == 2) ? pk_g2
                           : (m == 3) ? pk_e0 : (m == 4) ? pk_e1 : (m == 5) ? pk_e2
                           : (m == 6) ? pk_h0 : pk_h1;
        int idx = blk * 256 + threadIdx.x;      // 8192 = 128 frags * 64 lanes
        int f = idx >> 6, l = idx & 63;
        int ct = f >> 3, kb = f & 7, q = l >> 4, mm = l & 15;
        unsigned short out[8];
#pragma unroll
        for (int e = 0; e < 8; e++) {
            int k = kb * 32 + q * 4 + (e & 3) + ((e >> 2) << 4);
            out[e] = f2bf(W[(ct * 16 + mm) * HH + k]);
        }
        uint4 v;
        v.x = out[0] | ((unsigned)out[1] << 16);
        v.y = out[2] | ((unsigned)out[3] << 16);
        v.z = out[4] | ((unsigned)out[5] << 16);
        v.w = out[6] | ((unsigned)out[7] << 16);
        *(uint4*)(pk + idx * 8) = v;
    } else {
        // eWTb[j][c] = bf16(eW_ih0[c][j]); 32768 elems over 32 blocks x 256 thr x 4
        int base = blk * 256 + threadIdx.x;
#pragma unroll
        for (int k = 0; k < 4; k++) {
            int idx = base + k * 8192;
            int j = idx >> 8, c = idx & 255;
            eWTb[idx] = f2bf(eW_ih0[c * MM + j]);
        }
    }
}

// ---------------- X0B[b][t][i] = bf16(input @ gW_ih0^T + gb_ih0 + gb_hh0) ----------------
__global__ void k_x0(const float* __restrict__ x, const float* __restrict__ Wih0,
                     const float* __restrict__ bih0, const float* __restrict__ bhh0,
                     unsigned short* __restrict__ X0B) {
    int row = blockIdx.x;           // b*SS + t
    int i = threadIdx.x;
    const float4* xr = (const float4*)(x + row * DD);
    const float4* wr = (const float4*)(Wih0 + i * DD);
    float a0 = 0.f, a1 = 0.f, a2 = 0.f, a3 = 0.f;
#pragma unroll 8
    for (int k = 0; k < DD / 4; k++) {
        float4 xv = xr[k]; float4 wv = wr[k];
        a0 += xv.x * wv.x; a1 += xv.y * wv.y; a2 += xv.z * wv.z; a3 += xv.w * wv.w;
    }
    X0B[row * HH + i] = f2bf(a0 + a1 + a2 + a3 + bih0[i] + bhh0[i]);
}

// ---------------- MFMA fragment loaders ----------------
__device__ __forceinline__ bf16x8 ldA(const unsigned short* __restrict__ pk, int ct, int kb, int lane) {
    return *(const bf16x8*)(pk + (((ct * 8 + kb) * 64 + lane) << 3));
}
__device__ __forceinline__ bf16x8 ldBf(const unsigned short* base, int row, int kb, int q) {
    return *(const bf16x8*)(base + ((row * ROWG + kb * 4 + q) << 3));
}

// ---------------- graph RNN: one WG per batch; zero per-phase global ops ----------------
__global__ __launch_bounds__(512, 2) void k_graph_mfma(
    const unsigned short* __restrict__ X0B, const int* __restrict__ mask,
    const unsigned short* __restrict__ pk0,  // gW_hh0 packed
    const unsigned short* __restrict__ pk1,  // gW_ih1 packed
    const unsigned short* __restrict__ pk2,  // gW_hh1 packed
    const float* __restrict__ bih1, const float* __restrict__ bhh1,
    float* __restrict__ GS) {
    __shared__ alignas(16) unsigned short xs[SS * HH];   // 64 KB: X0 bf16
    __shared__ alignas(16) unsigned short gs[SS * HH];   // 64 KB: GS bf16
    __shared__ alignas(16) unsigned short h0b[2 * FB1];
    __shared__ alignas(16) unsigned short h1b[3 * FB1];
    __shared__ int lenS;

    int b = blockIdx.x;
    int tid = threadIdx.x;
    int wv = tid >> 6, lane = tid & 63;
    int q = lane >> 4, rr = lane & 15;
    int ct0 = 2 * wv;
    int m0 = 32 * wv + 4 * q;
    int g16off = (wv * 4 + q) << 3;

    // zero h buffers
    { unsigned* p = (unsigned*)h0b; for (int i = tid; i < FB1; i += 512) p[i] = 0; }
    { unsigned* p = (unsigned*)h1b; for (int i = tid; i < 3 * FB1 / 2; i += 512) p[i] = 0; }
    // stage X0 slice into LDS (64 KB coalesced)
    {
        const uint4* s = (const uint4*)(X0B + b * SS * HH);
        uint4* d = (uint4*)xs;
        for (int i = tid; i < SS * HH / 8; i += 512) d[i] = s[i];
    }
    if (wv == 0) {
        int s = mask[b * SS + lane] + mask[b * SS + 64 + lane];
        for (int off = 32; off; off >>= 1) s += __shfl_xor(s, off);
        if (lane == 0) lenS = s;
    }
    // weights -> registers (192/lane), pinned
    bf16x8 a0[2][8], a1[2][8], a2[2][8];
#pragma unroll
    for (int kb = 0; kb < 8; kb++) {
        a0[0][kb] = ldA(pk0, ct0, kb, lane); a0[1][kb] = ldA(pk0, ct0 + 1, kb, lane);
        a1[0][kb] = ldA(pk1, ct0, kb, lane); a1[1][kb] = ldA(pk1, ct0 + 1, kb, lane);
        a2[0][kb] = ldA(pk2, ct0, kb, lane); a2[1][kb] = ldA(pk2, ct0 + 1, kb, lane);
    }
#pragma unroll
    for (int kb = 0; kb < 8; kb++) {
        asm volatile("" : "+v"(a0[0][kb]), "+v"(a0[1][kb]),
                          "+v"(a1[0][kb]), "+v"(a1[1][kb]),
                          "+v"(a2[0][kb]), "+v"(a2[1][kb]));
    }
    f32x4 b1A = *(const f32x4*)(bih1 + m0) + *(const f32x4*)(bhh1 + m0);
    f32x4 b1B = *(const f32x4*)(bih1 + m0 + 16) + *(const f32x4*)(bhh1 + m0 + 16);
    __syncthreads();
    int len = lenS;                 // WG-uniform, len >= 64
    bool w0l = (rr == 0);

    // ---- phase 0: h0[0] = tanh(x[0]) ----
    {
        ushort4 xa = *(const ushort4*)(xs + m0);
        ushort4 xb = *(const ushort4*)(xs + m0 + 16);
        if (w0l) {
            uint4 nv = { pk2bf(ftanh(bfs(xa.x)), ftanh(bfs(xa.y))),
                         pk2bf(ftanh(bfs(xa.z)), ftanh(bfs(xa.w))),
                         pk2bf(ftanh(bfs(xb.x)), ftanh(bfs(xb.y))),
                         pk2bf(ftanh(bfs(xb.z)), ftanh(bfs(xb.w))) };
            *(uint4*)(h0b + g16off) = nv;
        }
    }
    __syncthreads();

    // x prefetch for t=1
    ushort4 xcA = *(const ushort4*)(xs + 256 + m0);
    ushort4 xcB = *(const ushort4*)(xs + 256 + m0 + 16);

    // ---- main phases t=1..len-1: h0[t] and h1[t-1], 1 barrier/phase, 0 VMEM ----
    int ir = 2, iw = 0;
    for (int t = 1; t < len; t++) {
        const unsigned short* h0r = h0b + ((t - 1) & 1) * FB1;
        const unsigned short* h1r = h1b + ir * FB1;
        int tn = (t + 1 < SS) ? t + 1 : t;
        ushort4 xnA = *(const ushort4*)(xs + tn * 256 + m0);
        ushort4 xnB = *(const ushort4*)(xs + tn * 256 + m0 + 16);
        f32x4 accA = { bfs(xcA.x), bfs(xcA.y), bfs(xcA.z), bfs(xcA.w) };
        f32x4 accB = { bfs(xcB.x), bfs(xcB.y), bfs(xcB.z), bfs(xcB.w) };
        f32x4 pAe = b1A, pBe = b1B;
        f32x4 pAh = {0.f,0.f,0.f,0.f}, pBh = {0.f,0.f,0.f,0.f};
#pragma unroll
        for (int kb = 0; kb < 8; kb++) {
            bf16x8 h = ldBf(h0r, 0, kb, q);
            bf16x8 g = ldBf(h1r, 0, kb, q);
            accA = __builtin_amdgcn_mfma_f32_16x16x32_bf16(a0[0][kb], h, accA, 0, 0, 0);
            accB = __builtin_amdgcn_mfma_f32_16x16x32_bf16(a0[1][kb], h, accB, 0, 0, 0);
            pAe  = __builtin_amdgcn_mfma_f32_16x16x32_bf16(a1[0][kb], h, pAe, 0, 0, 0);
            pBe  = __builtin_amdgcn_mfma_f32_16x16x32_bf16(a1[1][kb], h, pBe, 0, 0, 0);
            pAh  = __builtin_amdgcn_mfma_f32_16x16x32_bf16(a2[0][kb], g, pAh, 0, 0, 0);
            pBh  = __builtin_amdgcn_mfma_f32_16x16x32_bf16(a2[1][kb], g, pBh, 0, 0, 0);
        }
        if (w0l) {
            uint4 nv0 = { pk2bf(ftanh(accA[0]), ftanh(accA[1])), pk2bf(ftanh(accA[2]), ftanh(accA[3])),
                          pk2bf(ftanh(accB[0]), ftanh(accB[1])), pk2bf(ftanh(accB[2]), ftanh(accB[3])) };
            *(uint4*)(h0b + (t & 1) * FB1 + g16off) = nv0;
            f32x4 pA = pAe + pAh, pB = pBe + pBh;
            float eA[4], eB[4];
#pragma unroll
            for (int r = 0; r < 4; r++) { eA[r] = ftanh(pA[r]); eB[r] = ftanh(pB[r]); }
            uint4 nv1 = { pk2bf(eA[0], eA[1]), pk2bf(eA[2], eA[3]),
                          pk2bf(eB[0], eB[1]), pk2bf(eB[2], eB[3]) };
            *(uint4*)(h1b + iw * FB1 + g16off) = nv1;
            ushort4 ga = { f2bf(eA[0]), f2bf(eA[1]), f2bf(eA[2]), f2bf(eA[3]) };
            ushort4 gb = { f2bf(eB[0]), f2bf(eB[1]), f2bf(eB[2]), f2bf(eB[3]) };
            *(ushort4*)(gs + (t - 1) * 256 + m0) = ga;
            *(ushort4*)(gs + (t - 1) * 256 + m0 + 16) = gb;
        }
        __syncthreads();
        xcA = xnA; xcB = xnB;
        ir = (ir + 1 == 3) ? 0 : ir + 1;
        iw = (iw + 1 == 3) ? 0 : iw + 1;
    }

    // ---- tail: h1[len-1] -> gs[len-1] ----
    {
        const unsigned short* h0r = h0b + ((len - 1) & 1) * FB1;
        const unsigned short* h1r = h1b + ir * FB1;
        f32x4 pAe = b1A, pBe = b1B;
        f32x4 pAh = {0.f,0.f,0.f,0.f}, pBh = {0.f,0.f,0.f,0.f};
#pragma unroll
        for (int kb = 0; kb < 8; kb++) {
            bf16x8 h = ldBf(h0r, 0, kb, q);
            bf16x8 g = ldBf(h1r, 0, kb, q);
            pAe = __builtin_amdgcn_mfma_f32_16x16x32_bf16(a1[0][kb], h, pAe, 0, 0, 0);
            pBe = __builtin_amdgcn_mfma_f32_16x16x32_bf16(a1[1][kb], h, pBe, 0, 0, 0);
            pAh = __builtin_amdgcn_mfma_f32_16x16x32_bf16(a2[0][kb], g, pAh, 0, 0, 0);
            pBh = __builtin_amdgcn_mfma_f32_16x16x32_bf16(a2[1][kb], g, pBh, 0, 0, 0);
        }
        if (w0l) {
            f32x4 pA = pAe + pAh, pB = pBe + pBh;
            ushort4 ga = { f2bf(ftanh(pA[0])), f2bf(ftanh(pA[1])), f2bf(ftanh(pA[2])), f2bf(ftanh(pA[3])) };
            ushort4 gb = { f2bf(ftanh(pB[0])), f2bf(ftanh(pB[1])), f2bf(ftanh(pB[2])), f2bf(ftanh(pB[3])) };
            *(ushort4*)(gs + (len - 1) * 256 + m0) = ga;
            *(ushort4*)(gs + (len - 1) * 256 + m0 + 16) = gb;
        }
    }
    __syncthreads();
    // ---- flush gs -> GS (f32), zeros for t >= len ----
    {
        float* dst = GS + b * (SS * HH);
        const uint4* src = (const uint4*)gs;
        for (int i = tid; i < SS * HH / 8; i += 512) {
            int t = i >> 5;
            float4 f0 = {0.f,0.f,0.f,0.f}, f1 = {0.f,0.f,0.f,0.f};
            if (t < len) {
                uint4 v = src[i];
                f0 = float4{ bflo(v.x), bfhi(v.x), bflo(v.y), bfhi(v.y) };
                f1 = float4{ bflo(v.z), bfhi(v.z), bflo(v.w), bfhi(v.w) };
            }
            *(float4*)(dst + i * 8) = f0;
            *(float4*)(dst + i * 8 + 4) = f1;
        }
    }
}

// ---------------- edge RNN scan: merged phases + fused head/dep epilogue ----------------
// Phase j (j=0..128): layer0[j] (16 MFMA) + layer1[j-1] (32 MFMA) sharing the
// h0[j-1] B-fragments; xw0 rank-1 correction applied after B1 as linear fix-up.
__global__ __launch_bounds__(512, 2) void k_edge_mfma(
    const float* __restrict__ GS,
    const unsigned short* __restrict__ pk0,  // eW_hh0 packed
    const unsigned short* __restrict__ pk1,  // eW_ih1 packed
    const unsigned short* __restrict__ pk2,  // eW_hh1 packed
    const unsigned short* __restrict__ pkh,  // head_W packed
    const unsigned short* __restrict__ pkd,  // dep_W packed
    const unsigned short* __restrict__ eWTb, // eW_ih0^T bf16 (128 x 256)
    const float* __restrict__ bih0, const float* __restrict__ bhh0,
    const float* __restrict__ bih1, const float* __restrict__ bhh1,
    const float* __restrict__ clsW, const float* __restrict__ clsB,
    const float* __restrict__ headB, const float* __restrict__ depB,
    float* __restrict__ arc, float* __restrict__ headO, float* __restrict__ depO) {
    __shared__ alignas(16) unsigned short h0f[2 * FBE];
    __shared__ alignas(16) unsigned short h1f[2 * FBE];
    __shared__ alignas(16) unsigned short gsf[FBE];      // GS init frags (for heads)
    __shared__ alignas(16) unsigned short ews[MM * HH];  // 64 KB
    __shared__ float red[NW][GG];
    __shared__ float cws[HH];
    __shared__ float b1s[HH];
    __shared__ float arcb[GG][MM + 1];

    int tid = threadIdx.x;
    int wv = tid >> 6, lane = tid & 63;
    int q = lane >> 4, rr = lane & 15;
    int m0 = 32 * wv + 4 * q;
    int goff = (rr * ROWG + wv * 4 + q) << 3;
    int r0 = blockIdx.x * GG;

    // stage eWTb into LDS (64 KB coalesced)
    {
        const uint4* s = (const uint4*)eWTb;
        uint4* d = (uint4*)ews;
        for (int i = tid; i < MM * HH / 8; i += 512) d[i] = s[i];
    }
    // init frag buffers: h0[-1]=h1[-1]=gs (buf 1); zero buf 0 of h1 (phase-0 dummy reads)
    {
        int r = tid >> 5, g = tid & 31;           // g = kb*4 + qq
        int kb = g >> 2, qq = g & 3;
        int lo = kb * 32 + qq * 4;
        const float* gp = GS + (r0 + r) * HH + lo;
        float4 vlo = *(const float4*)gp;
        float4 vhi = *(const float4*)(gp + 16);
        uint4 pv = { pk2bf(vlo.x, vlo.y), pk2bf(vlo.z, vlo.w),
                     pk2bf(vhi.x, vhi.y), pk2bf(vhi.z, vhi.w) };
        int off = (r * ROWG + g) << 3;
        *(uint4*)(h0f + FBE + off) = pv;
        *(uint4*)(h1f + FBE + off) = pv;
        *(uint4*)(gsf + off) = pv;
        *(uint4*)(h1f + off) = uint4{0,0,0,0};
        *(uint4*)(h0f + off) = uint4{0,0,0,0};
    }
    if (tid < HH) {
        cws[tid] = clsW[tid];
        b1s[tid] = bih1[tid] + bhh1[tid];
    }
    // weights -> registers, pinned
    bf16x8 a0[2][8], a1[2][8], a2[2][8];
#pragma unroll
    for (int kb = 0; kb < 8; kb++) {
        a0[0][kb] = ldA(pk0, 2 * wv, kb, lane); a0[1][kb] = ldA(pk0, 2 * wv + 1, kb, lane);
        a1[0][kb] = ldA(pk1, 2 * wv, kb, lane); a1[1][kb] = ldA(pk1, 2 * wv + 1, kb, lane);
        a2[0][kb] = ldA(pk2, 2 * wv, kb, lane); a2[1][kb] = ldA(pk2, 2 * wv + 1, kb, lane);
    }
#pragma unroll
    for (int kb = 0; kb < 8; kb++) {
        asm volatile("" : "+v"(a0[0][kb]), "+v"(a0[1][kb]),
                          "+v"(a1[0][kb]), "+v"(a1[1][kb]),
                          "+v"(a2[0][kb]), "+v"(a2[1][kb]));
    }
    // xw0 in registers (D-layout)
    f32x4 xw0A = *(const f32x4*)(bih0 + m0) + *(const f32x4*)(bhh0 + m0);
    f32x4 xw0B = *(const f32x4*)(bih0 + m0 + 16) + *(const f32x4*)(bhh0 + m0 + 16);
    float clsb = clsB[0];
    int srow = (r0 + tid) & 127;
    __syncthreads();

    // ewc holds eW_ih0 column (j-1) slice entering phase j; phase 0 loads col 0.
    ushort4 ewcA, ewcB;

    for (int j = 0; j <= MM; j++) {
        const unsigned short* h0r = h0f + ((j + 1) & 1) * FBE;   // h0[j-1]
        const unsigned short* h1r = h1f + (j & 1) * FBE;         // h1[j-2]
        // prefetch ew column j (used as "col j-1" next phase)
        int jn = (j < MM) ? j : MM - 1;
        ushort4 ewnA = *(const ushort4*)(ews + jn * HH + m0);
        ushort4 ewnB = *(const ushort4*)(ews + jn * HH + m0 + 16);
        f32x4 acc0 = xw0A, acc1 = xw0B;                  // layer0[j]
        f32x4 p0e = *(const f32x4*)&b1s[m0];             // layer1[j-1] parts
        f32x4 p1e = *(const f32x4*)&b1s[m0 + 16];
        f32x4 p0h = {0.f,0.f,0.f,0.f}, p1h = {0.f,0.f,0.f,0.f};
#pragma unroll
        for (int kb = 0; kb < 8; kb++) {
            bf16x8 b0 = ldBf(h0r, rr, kb, q);            // shared: L0 + L1-e
            bf16x8 b1 = ldBf(h1r, rr, kb, q);
            acc0 = __builtin_amdgcn_mfma_f32_16x16x32_bf16(a0[0][kb], b0, acc0, 0, 0, 0);
            acc1 = __builtin_amdgcn_mfma_f32_16x16x32_bf16(a0[1][kb], b0, acc1, 0, 0, 0);
            p0e  = __builtin_amdgcn_mfma_f32_16x16x32_bf16(a1[0][kb], b0, p0e, 0, 0, 0);
            p1e  = __builtin_amdgcn_mfma_f32_16x16x32_bf16(a1[1][kb], b0, p1e, 0, 0, 0);
            p0h  = __builtin_amdgcn_mfma_f32_16x16x32_bf16(a2[0][kb], b1, p0h, 0, 0, 0);
            p1h  = __builtin_amdgcn_mfma_f32_16x16x32_bf16(a2[1][kb], b1, p1h, 0, 0, 0);
        }
        if (j > 0) {
            float e1a[4], e1b[4];
#pragma unroll
            for (int r = 0; r < 4; r++) { e1a[r] = ftanh(p0e[r] + p0h[r]); e1b[r] = ftanh(p1e[r] + p1h[r]); }
            // h1[j-1] frag write
            uint4 nv = { pk2bf(e1a[0], e1a[1]), pk2bf(e1a[2], e1a[3]),
                         pk2bf(e1b[0], e1b[1]), pk2bf(e1b[2], e1b[3]) };
            *(uint4*)(h1f + ((j + 1) & 1) * FBE + goff) = nv;
            // cls partial, reduce over q
            f32x4 cwA = *(const f32x4*)&cws[m0];
            f32x4 cwB = *(const f32x4*)&cws[m0 + 16];
            float part = cwA[0] * e1a[0] + cwA[1] * e1a[1] + cwA[2] * e1a[2] + cwA[3] * e1a[3]
                       + cwB[0] * e1b[0] + cwB[1] * e1b[1] + cwB[2] * e1b[2] + cwB[3] * e1b[3];
            part += __shfl_xor(part, 16);
            part += __shfl_xor(part, 32);
            if (lane < 16) red[wv][lane] = part;
        }
        __syncthreads();   // B1: red + h1[j-1] complete
        if (j > 0) {
            float s = clsb;
#pragma unroll
            for (int w = 0; w < NW; w++) s += red[w][rr];
            float edge = fsigm(s);
            f32x4 ewA = { bfs(ewcA.x), bfs(ewcA.y), bfs(ewcA.z), bfs(ewcA.w) };
            f32x4 ewB = { bfs(ewcB.x), bfs(ewcB.y), bfs(ewcB.z), bfs(ewcB.w) };
            xw0A += edge * ewA;  acc0 += edge * ewA;     // linear fix-up for col j-1
            xw0B += edge * ewB;  acc1 += edge * ewB;
            if (tid < GG) arcb[tid][j - 1] = ((j - 1) < srow) ? edge : 0.f;
        }
        if (j < MM) {
            uint4 nv = { pk2bf(ftanh(acc0[0]), ftanh(acc0[1])), pk2bf(ftanh(acc0[2]), ftanh(acc0[3])),
                         pk2bf(ftanh(acc1[0]), ftanh(acc1[1])), pk2bf(ftanh(acc1[2]), ftanh(acc1[3])) };
            *(uint4*)(h0f + (j & 1) * FBE + goff) = nv;
        }
        ewcA = ewnA; ewcB = ewnB;
        __syncthreads();   // B2: h0[j] complete
    }
    // ---- flush arc buffer ----
    for (int i = tid; i < GG * MM; i += 512) {
        int row = i & 15, j = i >> 4;
        int sr = (r0 + row) & 127, bi = (r0 + row) >> 7;
        arc[bi * (MM * SS) + j * SS + sr] = arcb[row][j];
    }
    // ---- fused heads: elu(GS @ W^T + b) via MFMA on gsf ----
    {
        f32x4 hA = *(const f32x4*)(headB + m0);
        f32x4 hB = *(const f32x4*)(headB + m0 + 16);
        f32x4 dA = *(const f32x4*)(depB + m0);
        f32x4 dB = *(const f32x4*)(depB + m0 + 16);
#pragma unroll
        for (int kb = 0; kb < 8; kb++) {
            bf16x8 bg = ldBf(gsf, rr, kb, q);
            hA = __builtin_amdgcn_mfma_f32_16x16x32_bf16(ldA(pkh, 2 * wv, kb, lane), bg, hA, 0, 0, 0);
            hB = __builtin_amdgcn_mfma_f32_16x16x32_bf16(ldA(pkh, 2 * wv + 1, kb, lane), bg, hB, 0, 0, 0);
            dA = __builtin_amdgcn_mfma_f32_16x16x32_bf16(ldA(pkd, 2 * wv, kb, lane), bg, dA, 0, 0, 0);
            dB = __builtin_amdgcn_mfma_f32_16x16x32_bf16(ldA(pkd, 2 * wv + 1, kb, lane), bg, dB, 0, 0, 0);
        }
        int row = r0 + rr;
        f32x4 oA, oB, eA, eB;
#pragma unroll
        for (int r = 0; r < 4; r++) {
            oA[r] = (hA[r] > 0.f) ? hA[r] : (__expf(hA[r]) - 1.0f);
            oB[r] = (hB[r] > 0.f) ? hB[r] : (__expf(hB[r]) - 1.0f);
            eA[r] = (dA[r] > 0.f) ? dA[r] : (__expf(dA[r]) - 1.0f);
            eB[r] = (dB[r] > 0.f) ? dB[r] : (__expf(dB[r]) - 1.0f);
        }
        *(f32x4*)(headO + row * TT + m0) = oA;
        *(f32x4*)(headO + row * TT + m0 + 16) = oB;
        *(f32x4*)(depO + row * TT + m0) = eA;
        *(f32x4*)(depO + row * TT + m0 + 16) = eB;
    }
}

extern "C" void kernel_launch(void* const* d_in, const int* in_sizes, int n_in,
                              void* d_out, int out_size, void* d_ws, size_t ws_size,
                              hipStream_t stream) {
    const float* input  = (const float*)d_in[0];
    const int*   mask   = (const int*)d_in[2];
    const float* gW_ih0 = (const float*)d_in[5];
    const float* gW_hh0 = (const float*)d_in[6];
    const float* gb_ih0 = (const float*)d_in[7];
    const float* gb_hh0 = (const float*)d_in[8];
    const float* gW_ih1 = (const float*)d_in[9];
    const float* gW_hh1 = (const float*)d_in[10];
    const float* gb_ih1 = (const float*)d_in[11];
    const float* gb_hh1 = (const float*)d_in[12];
    const float* eW_ih0 = (const float*)d_in[13];
    const float* eW_hh0 = (const float*)d_in[14];
    const float* eb_ih0 = (const float*)d_in[15];
    const float* eb_hh0 = (const float*)d_in[16];
    const float* eW_ih1 = (const float*)d_in[17];
    const float* eW_hh1 = (const float*)d_in[18];
    const float* eb_ih1 = (const float*)d_in[19];
    const float* eb_hh1 = (const float*)d_in[20];
    const float* cls_W  = (const float*)d_in[21];
    const float* cls_b  = (const float*)d_in[22];
    const float* head_W = (const float*)d_in[23];
    const float* head_b = (const float*)d_in[24];
    const float* dep_W  = (const float*)d_in[25];
    const float* dep_b  = (const float*)d_in[26];

    float* out      = (float*)d_out;
    float* head_out = out;                 // 8*128*256
    float* dep_out  = out + 262144;
    float* arc_out  = out + 524288;        // 8*128*128

    char* ws = (char*)d_ws;
    unsigned short* X0B = (unsigned short*)ws;                 // 512 KB bf16 [b][t][i]
    float* GS  = (float*)(ws + (1 << 20));                     // 1 MB
    unsigned short* pk_g0 = (unsigned short*)(ws + (2 << 20)); // 128 KB each
    unsigned short* pk_g1 = pk_g0 + 65536;
    unsigned short* pk_g2 = pk_g0 + 2 * 65536;
    unsigned short* pk_e0 = pk_g0 + 3 * 65536;
    unsigned short* pk_e1 = pk_g0 + 4 * 65536;
    unsigned short* pk_e2 = pk_g0 + 5 * 65536;
    unsigned short* pk_h0 = pk_g0 + 6 * 65536;
    unsigned short* pk_h1 = pk_g0 + 7 * 65536;
    unsigned short* eWTb  = pk_g0 + 8 * 65536;                 // 64 KB bf16

    k_prep<<<288, 256, 0, stream>>>(gW_hh0, gW_ih1, gW_hh1, eW_hh0, eW_ih1, eW_hh1,
                                    head_W, dep_W, eW_ih0,
                                    pk_g0, pk_g1, pk_g2, pk_e0, pk_e1, pk_e2,
                                    pk_h0, pk_h1, eWTb);
    k_x0<<<1024, 256, 0, stream>>>(input, gW_ih0, gb_ih0, gb_hh0, X0B);
    k_graph_mfma<<<8, 512, 0, stream>>>(X0B, mask, pk_g0, pk_g1, pk_g2, gb_ih1, gb_hh1, GS);
    k_edge_mfma<<<64, 512, 0, stream>>>(GS, pk_e0, pk_e1, pk_e2, pk_h0, pk_h1, eWTb,
                                        eb_ih0, eb_hh0, eb_ih1, eb_hh1, cls_W, cls_b,
                                        head_b, dep_b, arc_out, head_out, dep_out);
}